// Round 4
// baseline (1003.254 us; speedup 1.0000x reference)
//
#include <hip/hip_runtime.h>

typedef unsigned short u16;
typedef unsigned int u32;

#define NN 50000
#define NE 150000
#define D 42
#define EH 128
#define DD 1764   // D*D
#define STEPS 6
#define MS 48     // msg row stride (floats), 192 B = 16B-aligned
#define SCAN_NB 196  // (NN + 255) / 256

typedef __attribute__((ext_vector_type(8))) short bf8;
typedef __attribute__((ext_vector_type(4))) float f4;

static __device__ __forceinline__ float bf2f(u16 v) {
  return __uint_as_float(((u32)v) << 16);
}
static __device__ __forceinline__ u16 f2bf(float f) {
  u32 x = __float_as_uint(f);
  return (u16)((x + 0x7fffu + ((x >> 16) & 1u)) >> 16);  // RNE
}

// ---------------------------------------------------------------------------
// Dtype probe (bf16 vs fp32 inputs).
// ---------------------------------------------------------------------------
__global__ void k_detect(const u32* __restrict__ words, int* __restrict__ flag) {
  __shared__ int cnt;
  if (threadIdx.x == 0) cnt = 0;
  __syncthreads();
  int bad = 0;
  for (int i = threadIdx.x; i < 4096; i += 256) {
    u32 w = words[i];
    float v = __uint_as_float((w & 0xffffu) << 16);
    float a = fabsf(v);
    if (!(a < 16.0f)) bad++;
  }
  if (bad) atomicAdd(&cnt, bad);
  __syncthreads();
  if (threadIdx.x == 0) flag[0] = (cnt < 100) ? 1 : 0;
}

__global__ void k_cvt(const void* __restrict__ src, float* __restrict__ dst,
                      int count, const int* __restrict__ flag) {
  int i = blockIdx.x * blockDim.x + threadIdx.x;
  if (i >= count) return;
  if (flag[0]) dst[i] = bf2f(((const u16*)src)[i]);
  else         dst[i] = ((const float*)src)[i];
}

// ---------------------------------------------------------------------------
// CSR build: histogram of dst, hierarchical scan to row starts, rank assign.
// dst is constant across the 6 steps so this is once per launch.
// ---------------------------------------------------------------------------
__global__ void k_hist(const int* __restrict__ dstI, int* __restrict__ cnt) {
  int e = blockIdx.x * blockDim.x + threadIdx.x;
  if (e < NE) atomicAdd(&cnt[dstI[e]], 1);
}

// Phase A: per-block (256-wide) inclusive scan; block sums -> part[].
__global__ void k_scanA(const int* __restrict__ cnt, int* __restrict__ loc,
                        int* __restrict__ part) {
  __shared__ int wsum[4];
  int tid = threadIdx.x, wid = tid >> 6, lane = tid & 63;
  int i = blockIdx.x * 256 + tid;
  int v = (i < NN) ? cnt[i] : 0;
#pragma unroll
  for (int d = 1; d < 64; d <<= 1) {
    int t = __shfl_up(v, d, 64);
    if (lane >= d) v += t;
  }
  if (lane == 63) wsum[wid] = v;
  __syncthreads();
  if (tid == 0) {
    int s = 0;
#pragma unroll
    for (int w2 = 0; w2 < 4; ++w2) { int t = wsum[w2]; wsum[w2] = s; s += t; }
    part[blockIdx.x] = s;
  }
  __syncthreads();
  v += wsum[wid];
  if (i < NN) loc[i] = v;
}

// Phase B: single-block exclusive scan of part[SCAN_NB] in place.
__global__ void k_scanB(int* __restrict__ part) {
  __shared__ int wsum[4];
  int tid = threadIdx.x, wid = tid >> 6, lane = tid & 63;
  int v = (tid < SCAN_NB) ? part[tid] : 0;
  int orig = v;
#pragma unroll
  for (int d = 1; d < 64; d <<= 1) {
    int t = __shfl_up(v, d, 64);
    if (lane >= d) v += t;
  }
  if (lane == 63) wsum[wid] = v;
  __syncthreads();
  if (tid == 0) {
    int s = 0;
#pragma unroll
    for (int w2 = 0; w2 < 4; ++w2) { int t = wsum[w2]; wsum[w2] = s; s += t; }
  }
  __syncthreads();
  v += wsum[wid];
  if (tid < SCAN_NB) part[tid] = v - orig;  // exclusive
}

// Phase C: rs[0] = 0; rs[i+1] = loc[i] + part[i>>8].
__global__ void k_scanC(const int* __restrict__ loc, const int* __restrict__ part,
                        int* __restrict__ rs) {
  int i = blockIdx.x * 256 + threadIdx.x;
  if (i == 0) rs[0] = 0;
  if (i < NN) rs[i + 1] = loc[i] + part[blockIdx.x];
}

// rank[e] = sorted position of edge e; srcS[rank[e]] = src[e].
__global__ void k_rank(const int* __restrict__ dstI, const int* __restrict__ srcI,
                       int* __restrict__ cursor, int* __restrict__ rank,
                       int* __restrict__ srcS) {
  int e = blockIdx.x * blockDim.x + threadIdx.x;
  if (e >= NE) return;
  int p = atomicAdd(&cursor[dstI[e]], 1);
  rank[e] = p;
  srcS[p] = srcI[e];
}

// ---------------------------------------------------------------------------
// out0 = relu(n_feat @ lin0_w + lin0_b).  One wave per node, lane = out col.
// ---------------------------------------------------------------------------
__global__ void k_lin0(const float* __restrict__ nf, const float* __restrict__ w,
                       const float* __restrict__ b, float* __restrict__ outp) {
  int gid = blockIdx.x * blockDim.x + threadIdx.x;
  int n = gid >> 6, lane = gid & 63;
  if (n >= NN) return;
  float xv = (lane < D) ? nf[(size_t)n * D + lane] : 0.f;
  if (lane < D) {
    float acc = b[lane];
    for (int i = 0; i < D; ++i)
      acc += __shfl(xv, i, 64) * w[i * D + lane];
    outp[(size_t)n * D + lane] = fmaxf(acc, 0.f);
  }
}

// ---------------------------------------------------------------------------
// h_e = relu(e_feat @ en1_w + en1_b) -> bf16 [E][128], written in dst-sorted
// order (row rank[e]).
// ---------------------------------------------------------------------------
__global__ void k_en1(const float* __restrict__ ef, const float* __restrict__ w,
                      const float* __restrict__ b, const int* __restrict__ rank,
                      u16* __restrict__ h) {
  int gid = blockIdx.x * blockDim.x + threadIdx.x;
  int e = gid >> 7, k = gid & 127;
  if (e >= NE) return;
  float acc = b[k];
#pragma unroll
  for (int i = 0; i < 10; ++i)
    acc += ef[(size_t)e * 10 + i] * w[i * EH + k];
  h[(size_t)rank[e] * EH + k] = f2bf(fmaxf(acc, 0.f));
}

// ---------------------------------------------------------------------------
// Pack w2 into MFMA A-fragment order (bf16).
// A-frag for i-slice, kstep s, o-frag f: lane l holds 8 elems:
//   row o = f*16 + (l&15), k = s*32 + (l>>4)*8 + j,  value = w2[k, i, o]
// Element offset = (((i*4 + s)*3 + f)*64 + l)*8 + j.
// ---------------------------------------------------------------------------
__global__ void k_packA(const float* __restrict__ w2, u16* __restrict__ Ap) {
  int idx = blockIdx.x * 256 + threadIdx.x;
  if (idx >= D * 4 * 3 * 64 * 8) return;
  int j = idx & 7;
  int t = idx >> 3;
  int l = t & 63; t >>= 6;
  int f = t % 3;  t /= 3;
  int s = t & 3;
  int i = t >> 2;
  int k = s * 32 + ((l >> 4) << 3) + j;
  int o = f * 16 + (l & 15);
  float v = (o < D) ? w2[(size_t)k * DD + i * D + o] : 0.f;
  Ap[idx] = f2bf(v);
}

// b2 (en2_b reshaped [42][42]) packed as A-frags: row o, k = i-index.
__global__ void k_packB2(const float* __restrict__ e2b, u16* __restrict__ b2p) {
  int idx = blockIdx.x * 256 + threadIdx.x;
  if (idx >= 2 * 3 * 64 * 8) return;
  int j = idx & 7;
  int t = idx >> 3;
  int l = t & 63; t >>= 6;
  int f = t % 3;
  int s = t / 3;
  int k = s * 32 + ((l >> 4) << 3) + j;
  int o = f * 16 + (l & 15);
  float v = (k < D && o < D) ? e2b[k * D + o] : 0.f;
  b2p[idx] = f2bf(v);
}

// ---------------------------------------------------------------------------
// Fused NNConv message kernel, MFMA path. Edges are dst-sorted; messages are
// written LINEARLY to msg[E][MS] (no atomics).
//
// Wave decomposition: 2x2 (K-half x edge-half). Wave w: kh = w>>1 owns
// ksteps {2kh, 2kh+1}; eg = w&1 owns edges [eg*32, eg*32+32). The two
// ksteps are chained through the MFMA C-operand, so per i-slice the VALU
// scale-accumulate is 24 fmac (vs 48 in the 4-way K-split) and the
// cross-wave reduction is 2-way (one [64][52] buffer, 2 barriers).
// __launch_bounds__(256,3): (256,4) caps VGPR at 64 -> spills (proven R1).
// ---------------------------------------------------------------------------
__launch_bounds__(256, 3)
__global__ void k_edge_mfma(const float* __restrict__ outp, const u16* __restrict__ hbf,
                            const u16* __restrict__ Ap, const u16* __restrict__ b2p,
                            const int* __restrict__ srcS, float* __restrict__ msg) {
  // LDS: xT [42][64] f32 (10752 B) | region2: {hls 16KB + xbf 8KB}; red
  // [64][52] f32 (13312 B) overlays hls after compute.
  __shared__ __align__(16) char smem[10752 + 24576];
  float* xT = (float*)smem;
  char*  hls = smem + 10752;
  char*  xbf = smem + 10752 + 16384;
  float* red = (float*)(smem + 10752);

  int tid = threadIdx.x;
  long et = (long)blockIdx.x * 64;
  int ne = (int)(NE - et); if (ne > 64) ne = 64;

  // ---- stage h tile [64][128] bf16, XOR-swizzled rows ----
  for (int c = tid; c < 1024; c += 256) {
    int row = c >> 4;
    int off = (c & 15) << 4;  // byte offset within 256B row
    uint4 v = {0, 0, 0, 0};
    if (row < ne) v = *(const uint4*)(hbf + (et + row) * EH + (off >> 1));
    *(uint4*)(hls + row * 256 + (off ^ ((row & 7) << 4))) = v;
  }
  // ---- stage x = out[srcS[p]]: xT transposed f32 + xbf row-major bf16 (swizzled) ----
  {
    int r = tid >> 2, j = tid & 3;
    const float* xr = (r < ne) ? (outp + (size_t)srcS[et + r] * D) : nullptr;
    for (int i = j; i < D; i += 4) {
      float v = xr ? xr[i] : 0.f;
      xT[i * 64 + r] = v;
      int bo = (r * 128 + i * 2) ^ ((r & 7) << 4);
      *(u16*)(xbf + bo) = f2bf(v);
    }
    for (int i = D + j; i < 64; i += 4) {
      int bo = (r * 128 + i * 2) ^ ((r & 7) << 4);
      *(u16*)(xbf + bo) = 0;
    }
  }
  __syncthreads();

  int w = tid >> 6;
  int l = tid & 63;
  int e16 = l & 15;
  int kg = l >> 4;
  int kh = w >> 1;       // K-half: ksteps {2kh, 2kh+1}
  int eg = w & 1;        // edge-half: edges [eg*32, eg*32+32)

  // ---- hoist h B-frags: 2 local ksteps x 2 local edge-groups ----
  bf8 hf00, hf01, hf10, hf11;   // hf[s_local][g]
  {
    int sw = (e16 & 7) << 4;
    int r0 = eg * 32 + e16;        // g = 0
    int r1 = eg * 32 + 16 + e16;   // g = 1
    int kb0 = ((kh * 2 + 0) * 32 + kg * 8) * 2;
    int kb1 = ((kh * 2 + 1) * 32 + kg * 8) * 2;
    hf00 = *(const bf8*)(hls + r0 * 256 + (kb0 ^ sw));
    hf01 = *(const bf8*)(hls + r1 * 256 + (kb0 ^ sw));
    hf10 = *(const bf8*)(hls + r0 * 256 + (kb1 ^ sw));
    hf11 = *(const bf8*)(hls + r1 * 256 + (kb1 ^ sw));
  }

  f4 macc[2][3];
#pragma unroll
  for (int g = 0; g < 2; ++g)
#pragma unroll
    for (int f = 0; f < 3; ++f)
      macc[g][f] = (f4){0.f, 0.f, 0.f, 0.f};

  // A-frag base for this wave's K-half: frag(i, s_local, f) at
  // apw + i*6144 + s_local*1536 + f*512  (u16 units)
  const u16* apw = Ap + (size_t)(kh * 2) * 1536 + (size_t)l * 8;

#define LOADA(dst, ii)                                                          \
  {                                                                             \
    const u16* p_ = apw + (size_t)(ii) * 6144;                                  \
    dst[0] = *(const bf8*)(p_);                                                 \
    dst[1] = *(const bf8*)(p_ + 512);                                           \
    dst[2] = *(const bf8*)(p_ + 1024);                                          \
    dst[3] = *(const bf8*)(p_ + 1536);                                          \
    dst[4] = *(const bf8*)(p_ + 2048);                                          \
    dst[5] = *(const bf8*)(p_ + 2560);                                          \
  }

#define COMPUTE(ii, AA)                                                         \
  {                                                                             \
    f4 zz = {0.f, 0.f, 0.f, 0.f};                                               \
    f4 q0, q1, q2;                                                              \
    /* g = 0 */                                                                 \
    q0 = __builtin_amdgcn_mfma_f32_16x16x32_bf16(AA[0], hf00, zz, 0, 0, 0);     \
    q1 = __builtin_amdgcn_mfma_f32_16x16x32_bf16(AA[1], hf00, zz, 0, 0, 0);     \
    q2 = __builtin_amdgcn_mfma_f32_16x16x32_bf16(AA[2], hf00, zz, 0, 0, 0);     \
    q0 = __builtin_amdgcn_mfma_f32_16x16x32_bf16(AA[3], hf10, q0, 0, 0, 0);     \
    q1 = __builtin_amdgcn_mfma_f32_16x16x32_bf16(AA[4], hf10, q1, 0, 0, 0);     \
    q2 = __builtin_amdgcn_mfma_f32_16x16x32_bf16(AA[5], hf10, q2, 0, 0, 0);     \
    float xs0 = xT[(ii) * 64 + eg * 32 + e16];                                  \
    macc[0][0] += xs0 * q0;                                                     \
    macc[0][1] += xs0 * q1;                                                     \
    macc[0][2] += xs0 * q2;                                                     \
    /* g = 1 */                                                                 \
    q0 = __builtin_amdgcn_mfma_f32_16x16x32_bf16(AA[0], hf01, zz, 0, 0, 0);     \
    q1 = __builtin_amdgcn_mfma_f32_16x16x32_bf16(AA[1], hf01, zz, 0, 0, 0);     \
    q2 = __builtin_amdgcn_mfma_f32_16x16x32_bf16(AA[2], hf01, zz, 0, 0, 0);     \
    q0 = __builtin_amdgcn_mfma_f32_16x16x32_bf16(AA[3], hf11, q0, 0, 0, 0);     \
    q1 = __builtin_amdgcn_mfma_f32_16x16x32_bf16(AA[4], hf11, q1, 0, 0, 0);     \
    q2 = __builtin_amdgcn_mfma_f32_16x16x32_bf16(AA[5], hf11, q2, 0, 0, 0);     \
    float xs1 = xT[(ii) * 64 + eg * 32 + 16 + e16];                             \
    macc[1][0] += xs1 * q0;                                                     \
    macc[1][1] += xs1 * q1;                                                     \
    macc[1][2] += xs1 * q2;                                                     \
  }

  // ---- main loop over 42 i-slices, A double-buffered ----
  bf8 A0[6], A1[6];
  LOADA(A0, 0);
#pragma unroll 1
  for (int i = 0; i < D; i += 2) {
    LOADA(A1, i + 1);
    COMPUTE(i, A0);
    if (i + 2 < D) LOADA(A0, i + 2);
    COMPUTE(i + 1, A1);
  }

  // ---- b2 epilogue: each wave adds its K-half's b2 kstep for its edges ----
  {
    const u16* bpw = b2p + (size_t)kh * 1536 + (size_t)l * 8;
    bf8 B0 = *(const bf8*)(bpw);
    bf8 B1 = *(const bf8*)(bpw + 512);
    bf8 B2 = *(const bf8*)(bpw + 1024);
    int kb = (kh * 32 + kg * 8) * 2;
#pragma unroll
    for (int g = 0; g < 2; ++g) {
      int row = eg * 32 + g * 16 + e16;
      bf8 bx = *(const bf8*)(xbf + ((row * 128 + kb) ^ ((row & 7) << 4)));
      macc[g][0] = __builtin_amdgcn_mfma_f32_16x16x32_bf16(B0, bx, macc[g][0], 0, 0, 0);
      macc[g][1] = __builtin_amdgcn_mfma_f32_16x16x32_bf16(B1, bx, macc[g][1], 0, 0, 0);
      macc[g][2] = __builtin_amdgcn_mfma_f32_16x16x32_bf16(B2, bx, macc[g][2], 0, 0, 0);
    }
  }

  // ---- 2-way cross-wave reduction through LDS (red overlays hls) ----
  __syncthreads();
  if (kh == 1) {
#pragma unroll
    for (int g = 0; g < 2; ++g)
#pragma unroll
      for (int f = 0; f < 3; ++f)
        *(f4*)&red[(size_t)(eg * 32 + g * 16 + e16) * 52 + f * 16 + kg * 4] = macc[g][f];
  }
  __syncthreads();
  if (kh == 0) {
#pragma unroll
    for (int g = 0; g < 2; ++g) {
      int e = eg * 32 + g * 16 + e16;
      if (e < ne) {
        float* mrow = msg + (size_t)(et + e) * MS;
#pragma unroll
        for (int f = 0; f < 3; ++f) {
          f4 v = *(f4*)&red[(size_t)e * 52 + f * 16 + kg * 4];
          v += macc[g][f];
          *(f4*)(mrow + f * 16 + kg * 4) = v;   // cols >= 42 are pad
        }
      }
    }
  }
#undef COMPUTE
#undef LOADA
}

// ---------------------------------------------------------------------------
// Node update with fused CSR aggregation:
// aggr = sum over msg rows [rs[n], rs[n+1]); m = relu(aggr + out + conv_bias);
// out_new = concat([m, out]) @ msg_w + msg_b;  last step: d_out = out_new + n_feat
// CSR gather is 4-wide with clamped indices so 4 independent loads are in
// flight per iteration.
// ---------------------------------------------------------------------------
__global__ void k_node_update(const float* __restrict__ msg, const int* __restrict__ rs,
                              const float* __restrict__ outp,
                              const float* __restrict__ cb, const float* __restrict__ mw,
                              const float* __restrict__ mb, float* __restrict__ newout,
                              const float* __restrict__ nf, void* __restrict__ fout,
                              int last, const int* __restrict__ flag) {
  int gid = blockIdx.x * blockDim.x + threadIdx.x;
  int n = gid >> 6, lane = gid & 63;
  if (n >= NN) return;
  float ov = (lane < D) ? outp[(size_t)n * D + lane] : 0.f;
  float av = 0.f;
  int r0 = rs[n], r1 = rs[n + 1];
  if (lane < D && r0 < r1) {
    float a0 = 0.f, a1 = 0.f, a2 = 0.f, a3 = 0.f;
    for (int r = r0; r < r1; r += 4) {
      int i1 = (r + 1 < r1) ? r + 1 : r;
      int i2 = (r + 2 < r1) ? r + 2 : r;
      int i3 = (r + 3 < r1) ? r + 3 : r;
      float v0 = msg[(size_t)r  * MS + lane];
      float v1 = msg[(size_t)i1 * MS + lane];
      float v2 = msg[(size_t)i2 * MS + lane];
      float v3 = msg[(size_t)i3 * MS + lane];
      a0 += v0;
      a1 += (r + 1 < r1) ? v1 : 0.f;
      a2 += (r + 2 < r1) ? v2 : 0.f;
      a3 += (r + 3 < r1) ? v3 : 0.f;
    }
    av = (a0 + a1) + (a2 + a3);
  }
  float mv = 0.f;
  if (lane < D) mv = fmaxf(av + ov + cb[lane], 0.f);
  if (lane < D) {
    float acc = mb[lane];
    for (int i = 0; i < D; ++i)
      acc += __shfl(mv, i, 64) * mw[i * D + lane];
    for (int i = 0; i < D; ++i)
      acc += __shfl(ov, i, 64) * mw[(D + i) * D + lane];
    size_t idx = (size_t)n * D + lane;
    if (last) {
      float res = acc + nf[idx];
      if (flag[0]) ((u16*)fout)[idx] = f2bf(res);
      else         ((float*)fout)[idx] = res;
    } else {
      newout[idx] = acc;
    }
  }
}

// ---------------------------------------------------------------------------
extern "C" void kernel_launch(void* const* d_in, const int* in_sizes, int n_in,
                              void* d_out, int out_size, void* d_ws, size_t ws_size,
                              hipStream_t stream) {
  (void)in_sizes; (void)n_in; (void)out_size; (void)ws_size;
  const void* nf   = d_in[0];
  const void* ef   = d_in[1];
  const int*  srcI = (const int*)d_in[2];
  const int*  dstI = (const int*)d_in[3];
  const void* l0w = d_in[4];  const void* l0b = d_in[5];
  const void* e1w = d_in[6];  const void* e1b = d_in[7];
  const void* e2w = d_in[8];  const void* e2b = d_in[9];
  const void* cbI = d_in[10]; const void* mwI = d_in[11]; const void* mbI = d_in[12];

  char* ws = (char*)d_ws;
  size_t off = 0;
  auto alloc = [&](size_t bytes) -> void* {
    void* p = ws + off;
    off = (off + bytes + 255) & ~(size_t)255;
    return p;
  };

  int*   flag  = (int*)alloc(4);
  float* c_nf  = (float*)alloc((size_t)NN * D * 4);
  float* c_ef  = (float*)alloc((size_t)NE * 10 * 4);
  float* c_l0w = (float*)alloc(D * D * 4);
  float* c_l0b = (float*)alloc(D * 4);
  float* c_e1w = (float*)alloc(10 * EH * 4);
  float* c_e1b = (float*)alloc(EH * 4);
  float* c_e2w = (float*)alloc((size_t)EH * DD * 4);
  float* c_e2b = (float*)alloc(DD * 4);
  float* c_cb  = (float*)alloc(D * 4);
  float* c_mw  = (float*)alloc(2 * D * D * 4);
  float* c_mb  = (float*)alloc(D * 4);
  float* out_a = (float*)alloc((size_t)NN * D * 4);
  float* out_b = (float*)alloc((size_t)NN * D * 4);
  u16*   hbf   = (u16*)alloc((size_t)NE * EH * 2);
  u16*   Ap    = (u16*)alloc((size_t)D * 4 * 3 * 64 * 8 * 2);
  u16*   b2p   = (u16*)alloc((size_t)2 * 3 * 64 * 8 * 2);
  int*   cnt    = (int*)alloc((size_t)NN * 4);
  int*   loc    = (int*)alloc((size_t)NN * 4);
  int*   part   = (int*)alloc((size_t)SCAN_NB * 4);
  int*   rowst  = (int*)alloc((size_t)(NN + 1) * 4);
  int*   cursor = (int*)alloc((size_t)NN * 4);
  int*   rank   = (int*)alloc((size_t)NE * 4);
  int*   srcS   = (int*)alloc((size_t)NE * 4);
  float* msg    = (float*)alloc((size_t)NE * MS * 4);

  // dtype probe + canonicalization to fp32
  k_detect<<<1, 256, 0, stream>>>((const u32*)nf, flag);
  auto cvt = [&](const void* s, float* dPtr, int count) {
    k_cvt<<<(count + 255) / 256, 256, 0, stream>>>(s, dPtr, count, flag);
  };
  cvt(nf,  c_nf,  NN * D);
  cvt(ef,  c_ef,  NE * 10);
  cvt(l0w, c_l0w, D * D);
  cvt(l0b, c_l0b, D);
  cvt(e1w, c_e1w, 10 * EH);
  cvt(e1b, c_e1b, EH);
  cvt(e2w, c_e2w, EH * DD);
  cvt(e2b, c_e2b, DD);
  cvt(cbI, c_cb,  D);
  cvt(mwI, c_mw,  2 * D * D);
  cvt(mbI, c_mb,  D);

  // CSR build (dst constant across steps — once per launch)
  (void)hipMemsetAsync(cnt, 0, (size_t)NN * 4, stream);
  k_hist<<<(NE + 255) / 256, 256, 0, stream>>>(dstI, cnt);
  k_scanA<<<SCAN_NB, 256, 0, stream>>>(cnt, loc, part);
  k_scanB<<<1, 256, 0, stream>>>(part);
  k_scanC<<<SCAN_NB, 256, 0, stream>>>(loc, part, rowst);
  (void)hipMemcpyAsync(cursor, rowst, (size_t)NN * 4, hipMemcpyDeviceToDevice, stream);
  k_rank<<<(NE + 255) / 256, 256, 0, stream>>>(dstI, srcI, cursor, rank, srcS);

  // node init + edge network (dst-sorted) + fragment packing
  k_lin0<<<(NN * 64 + 255) / 256, 256, 0, stream>>>(c_nf, c_l0w, c_l0b, out_a);
  k_en1<<<(NE * 128 + 255) / 256, 256, 0, stream>>>(c_ef, c_e1w, c_e1b, rank, hbf);
  k_packA<<<(D * 4 * 3 * 64 * 8 + 255) / 256, 256, 0, stream>>>(c_e2w, Ap);
  k_packB2<<<(2 * 3 * 64 * 8 + 255) / 256, 256, 0, stream>>>(c_e2b, b2p);

  int nblk = (NE + 63) / 64;
  float* cur = out_a;
  float* nxt = out_b;
  for (int s = 0; s < STEPS; ++s) {
    k_edge_mfma<<<nblk, 256, 0, stream>>>(cur, hbf, Ap, b2p, srcS, msg);
    int last = (s == STEPS - 1) ? 1 : 0;
    k_node_update<<<(NN * 64 + 255) / 256, 256, 0, stream>>>(
        msg, rowst, cur, c_cb, c_mw, c_mb, nxt, c_nf, d_out, last, flag);
    float* t = cur; cur = nxt; nxt = t;
  }
}

// Round 5
// 950.123 us; speedup vs baseline: 1.0559x; 1.0559x over previous
//
#include <hip/hip_runtime.h>

typedef unsigned short u16;
typedef unsigned int u32;

#define NN 50000
#define NE 150000
#define D 42
#define EH 128
#define DD 1764   // D*D
#define STEPS 6
#define MS 48     // msg row stride (floats), 192 B = 16B-aligned
#define SCAN_NB 196  // (NN + 255) / 256

typedef __attribute__((ext_vector_type(8))) short bf8;
typedef __attribute__((ext_vector_type(4))) float f4;

static __device__ __forceinline__ float bf2f(u16 v) {
  return __uint_as_float(((u32)v) << 16);
}
static __device__ __forceinline__ u16 f2bf(float f) {
  u32 x = __float_as_uint(f);
  return (u16)((x + 0x7fffu + ((x >> 16) & 1u)) >> 16);  // RNE
}

// ---------------------------------------------------------------------------
// Dtype probe (bf16 vs fp32 inputs).
// ---------------------------------------------------------------------------
__global__ void k_detect(const u32* __restrict__ words, int* __restrict__ flag) {
  __shared__ int cnt;
  if (threadIdx.x == 0) cnt = 0;
  __syncthreads();
  int bad = 0;
  for (int i = threadIdx.x; i < 4096; i += 256) {
    u32 w = words[i];
    float v = __uint_as_float((w & 0xffffu) << 16);
    float a = fabsf(v);
    if (!(a < 16.0f)) bad++;
  }
  if (bad) atomicAdd(&cnt, bad);
  __syncthreads();
  if (threadIdx.x == 0) flag[0] = (cnt < 100) ? 1 : 0;
}

__global__ void k_cvt(const void* __restrict__ src, float* __restrict__ dst,
                      int count, const int* __restrict__ flag) {
  int i = blockIdx.x * blockDim.x + threadIdx.x;
  if (i >= count) return;
  if (flag[0]) dst[i] = bf2f(((const u16*)src)[i]);
  else         dst[i] = ((const float*)src)[i];
}

// ---------------------------------------------------------------------------
// CSR build: histogram of dst, hierarchical scan to row starts, rank assign.
// dst is constant across the 6 steps so this is once per launch.
// ---------------------------------------------------------------------------
__global__ void k_hist(const int* __restrict__ dstI, int* __restrict__ cnt) {
  int e = blockIdx.x * blockDim.x + threadIdx.x;
  if (e < NE) atomicAdd(&cnt[dstI[e]], 1);
}

// Phase A: per-block (256-wide) inclusive scan; block sums -> part[].
__global__ void k_scanA(const int* __restrict__ cnt, int* __restrict__ loc,
                        int* __restrict__ part) {
  __shared__ int wsum[4];
  int tid = threadIdx.x, wid = tid >> 6, lane = tid & 63;
  int i = blockIdx.x * 256 + tid;
  int v = (i < NN) ? cnt[i] : 0;
#pragma unroll
  for (int d = 1; d < 64; d <<= 1) {
    int t = __shfl_up(v, d, 64);
    if (lane >= d) v += t;
  }
  if (lane == 63) wsum[wid] = v;
  __syncthreads();
  if (tid == 0) {
    int s = 0;
#pragma unroll
    for (int w2 = 0; w2 < 4; ++w2) { int t = wsum[w2]; wsum[w2] = s; s += t; }
    part[blockIdx.x] = s;
  }
  __syncthreads();
  v += wsum[wid];
  if (i < NN) loc[i] = v;
}

// Phase B: single-block exclusive scan of part[SCAN_NB] in place.
__global__ void k_scanB(int* __restrict__ part) {
  __shared__ int wsum[4];
  int tid = threadIdx.x, wid = tid >> 6, lane = tid & 63;
  int v = (tid < SCAN_NB) ? part[tid] : 0;
  int orig = v;
#pragma unroll
  for (int d = 1; d < 64; d <<= 1) {
    int t = __shfl_up(v, d, 64);
    if (lane >= d) v += t;
  }
  if (lane == 63) wsum[wid] = v;
  __syncthreads();
  if (tid == 0) {
    int s = 0;
#pragma unroll
    for (int w2 = 0; w2 < 4; ++w2) { int t = wsum[w2]; wsum[w2] = s; s += t; }
  }
  __syncthreads();
  v += wsum[wid];
  if (tid < SCAN_NB) part[tid] = v - orig;  // exclusive
}

// Phase C: rs[0] = 0; rs[i+1] = loc[i] + part[i>>8].
__global__ void k_scanC(const int* __restrict__ loc, const int* __restrict__ part,
                        int* __restrict__ rs) {
  int i = blockIdx.x * 256 + threadIdx.x;
  if (i == 0) rs[0] = 0;
  if (i < NN) rs[i + 1] = loc[i] + part[blockIdx.x];
}

// rank[e] = sorted position of edge e; srcS[rank[e]] = src[e].
__global__ void k_rank(const int* __restrict__ dstI, const int* __restrict__ srcI,
                       int* __restrict__ cursor, int* __restrict__ rank,
                       int* __restrict__ srcS) {
  int e = blockIdx.x * blockDim.x + threadIdx.x;
  if (e >= NE) return;
  int p = atomicAdd(&cursor[dstI[e]], 1);
  rank[e] = p;
  srcS[p] = srcI[e];
}

// ---------------------------------------------------------------------------
// out0 = relu(n_feat @ lin0_w + lin0_b).  One wave per node, lane = out col.
// ---------------------------------------------------------------------------
__global__ void k_lin0(const float* __restrict__ nf, const float* __restrict__ w,
                       const float* __restrict__ b, float* __restrict__ outp) {
  int gid = blockIdx.x * blockDim.x + threadIdx.x;
  int n = gid >> 6, lane = gid & 63;
  if (n >= NN) return;
  float xv = (lane < D) ? nf[(size_t)n * D + lane] : 0.f;
  if (lane < D) {
    float acc = b[lane];
    for (int i = 0; i < D; ++i)
      acc += __shfl(xv, i, 64) * w[i * D + lane];
    outp[(size_t)n * D + lane] = fmaxf(acc, 0.f);
  }
}

// ---------------------------------------------------------------------------
// h_e = relu(e_feat @ en1_w + en1_b) -> bf16 [E][128], written in dst-sorted
// order (row rank[e]).
// ---------------------------------------------------------------------------
__global__ void k_en1(const float* __restrict__ ef, const float* __restrict__ w,
                      const float* __restrict__ b, const int* __restrict__ rank,
                      u16* __restrict__ h) {
  int gid = blockIdx.x * blockDim.x + threadIdx.x;
  int e = gid >> 7, k = gid & 127;
  if (e >= NE) return;
  float acc = b[k];
#pragma unroll
  for (int i = 0; i < 10; ++i)
    acc += ef[(size_t)e * 10 + i] * w[i * EH + k];
  h[(size_t)rank[e] * EH + k] = f2bf(fmaxf(acc, 0.f));
}

// ---------------------------------------------------------------------------
// Pack w2 into MFMA A-fragment order (bf16).
// A-frag for i-slice, kstep s, o-frag f: lane l holds 8 elems:
//   row o = f*16 + (l&15), k = s*32 + (l>>4)*8 + j,  value = w2[k, i, o]
// Element offset = (((i*4 + s)*3 + f)*64 + l)*8 + j.
// ---------------------------------------------------------------------------
__global__ void k_packA(const float* __restrict__ w2, u16* __restrict__ Ap) {
  int idx = blockIdx.x * 256 + threadIdx.x;
  if (idx >= D * 4 * 3 * 64 * 8) return;
  int j = idx & 7;
  int t = idx >> 3;
  int l = t & 63; t >>= 6;
  int f = t % 3;  t /= 3;
  int s = t & 3;
  int i = t >> 2;
  int k = s * 32 + ((l >> 4) << 3) + j;
  int o = f * 16 + (l & 15);
  float v = (o < D) ? w2[(size_t)k * DD + i * D + o] : 0.f;
  Ap[idx] = f2bf(v);
}

// b2 (en2_b reshaped [42][42]) packed as A-frags: row o, k = i-index.
__global__ void k_packB2(const float* __restrict__ e2b, u16* __restrict__ b2p) {
  int idx = blockIdx.x * 256 + threadIdx.x;
  if (idx >= 2 * 3 * 64 * 8) return;
  int j = idx & 7;
  int t = idx >> 3;
  int l = t & 63; t >>= 6;
  int f = t % 3;
  int s = t / 3;
  int k = s * 32 + ((l >> 4) << 3) + j;
  int o = f * 16 + (l & 15);
  float v = (k < D && o < D) ? e2b[k * D + o] : 0.f;
  b2p[idx] = f2bf(v);
}

// ---------------------------------------------------------------------------
// Fused NNConv message kernel, MFMA path. Edges are dst-sorted; messages are
// written LINEARLY to msg[E][MS] (no atomics).
//
// Round-3 decomposition (proven 103.5 us): wave = kstep (4-way K-split),
// 4 edge-groups per wave, LDS 2-stage reduction.
// This round: A-frag prefetch depth 2 (4 rotating buffers). One COMPUTE is
// ~150 issue-cycles but L2 hit latency is ~200 cyc, so the old depth-1
// double buffer stalled every iteration on vmcnt; depth 2 gives ~450 cyc
// of cover.  WRITE_SIZE == 28125 KB is the no-spill sentinel.
// __launch_bounds__(256,3): (256,4) caps VGPR at 64 -> spills (proven R1).
// ---------------------------------------------------------------------------
__launch_bounds__(256, 3)
__global__ void k_edge_mfma(const float* __restrict__ outp, const u16* __restrict__ hbf,
                            const u16* __restrict__ Ap, const u16* __restrict__ b2p,
                            const int* __restrict__ srcS, float* __restrict__ msg) {
  // LDS: xT [42][64] f32 (10752 B) | region2: {hls 16KB + xbf 8KB} later {red [2][64][52] f32 = 26624 B}
  __shared__ __align__(16) char smem[10752 + 26624];
  float* xT = (float*)smem;
  char*  hls = smem + 10752;
  char*  xbf = smem + 10752 + 16384;
  float* red = (float*)(smem + 10752);

  int tid = threadIdx.x;
  long et = (long)blockIdx.x * 64;
  int ne = (int)(NE - et); if (ne > 64) ne = 64;

  // ---- stage h tile [64][128] bf16, XOR-swizzled rows ----
  for (int c = tid; c < 1024; c += 256) {
    int row = c >> 4;
    int off = (c & 15) << 4;  // byte offset within 256B row
    uint4 v = {0, 0, 0, 0};
    if (row < ne) v = *(const uint4*)(hbf + (et + row) * EH + (off >> 1));
    *(uint4*)(hls + row * 256 + (off ^ ((row & 7) << 4))) = v;
  }
  // ---- stage x = out[srcS[p]]: xT transposed f32 + xbf row-major bf16 (swizzled) ----
  {
    int r = tid >> 2, j = tid & 3;
    const float* xr = (r < ne) ? (outp + (size_t)srcS[et + r] * D) : nullptr;
    for (int i = j; i < D; i += 4) {
      float v = xr ? xr[i] : 0.f;
      xT[i * 64 + r] = v;
      int bo = (r * 128 + i * 2) ^ ((r & 7) << 4);
      *(u16*)(xbf + bo) = f2bf(v);
    }
    for (int i = D + j; i < 64; i += 4) {
      int bo = (r * 128 + i * 2) ^ ((r & 7) << 4);
      *(u16*)(xbf + bo) = 0;
    }
  }
  __syncthreads();

  int w = tid >> 6;   // wave id = k-step
  int l = tid & 63;
  int e16 = l & 15;
  int kg = l >> 4;

  // ---- hoist h B-frags (one k-step, 4 edge-groups) into registers ----
  bf8 hf[4];
  {
    int kb = (w * 32 + kg * 8) * 2;
    int sw = (e16 & 7) << 4;
#pragma unroll
    for (int g = 0; g < 4; ++g)
      hf[g] = *(const bf8*)(hls + (g * 16 + e16) * 256 + (kb ^ sw));
  }

  f4 macc[4][3];
#pragma unroll
  for (int g = 0; g < 4; ++g)
#pragma unroll
    for (int f = 0; f < 3; ++f)
      macc[g][f] = (f4){0.f, 0.f, 0.f, 0.f};

  const u16* apw = Ap + (size_t)w * 1536 + (size_t)l * 8;

#define LOADA(dst, ii)                                                          \
  {                                                                             \
    const u16* p_ = apw + (size_t)(ii) * 6144;                                  \
    dst[0] = *(const bf8*)(p_);                                                 \
    dst[1] = *(const bf8*)(p_ + 512);                                           \
    dst[2] = *(const bf8*)(p_ + 1024);                                          \
  }

#define COMPUTE(ii, AA)                                                         \
  {                                                                             \
    _Pragma("unroll")                                                           \
    for (int g = 0; g < 4; ++g) {                                               \
      float xs = xT[(ii) * 64 + g * 16 + e16];                                  \
      f4 zz = {0.f, 0.f, 0.f, 0.f};                                             \
      f4 q0 = __builtin_amdgcn_mfma_f32_16x16x32_bf16(AA[0], hf[g], zz, 0, 0, 0); \
      f4 q1 = __builtin_amdgcn_mfma_f32_16x16x32_bf16(AA[1], hf[g], zz, 0, 0, 0); \
      f4 q2 = __builtin_amdgcn_mfma_f32_16x16x32_bf16(AA[2], hf[g], zz, 0, 0, 0); \
      macc[g][0] += xs * q0;                                                    \
      macc[g][1] += xs * q1;                                                    \
      macc[g][2] += xs * q2;                                                    \
    }                                                                           \
  }

  // ---- main loop over 42 i-slices, 4-buffer rotation, prefetch depth 2 ----
  bf8 B0[3], B1[3], B2[3], B3[3];
  LOADA(B0, 0); LOADA(B1, 1); LOADA(B2, 2); LOADA(B3, 3);
#pragma unroll 1
  for (int i = 0; i < 40; i += 4) {
    COMPUTE(i, B0);     { int n0 = i + 4; if (n0 >= D) n0 = 0; LOADA(B0, n0); }
    COMPUTE(i + 1, B1); { int n1 = i + 5; if (n1 >= D) n1 = 0; LOADA(B1, n1); }
    COMPUTE(i + 2, B2); { int n2 = i + 6; if (n2 >= D) n2 = 0; LOADA(B2, n2); }
    COMPUTE(i + 3, B3); { int n3 = i + 7; if (n3 >= D) n3 = 0; LOADA(B3, n3); }
  }
  COMPUTE(40, B0);
  COMPUTE(41, B1);

  // ---- b2 epilogue: waves 0,1 add (x @ b2)^T via 2 k-steps over i ----
  if (w < 2) {
    const u16* bpw = b2p + (size_t)w * 1536 + (size_t)l * 8;
    bf8 Bb0 = *(const bf8*)(bpw);
    bf8 Bb1 = *(const bf8*)(bpw + 512);
    bf8 Bb2 = *(const bf8*)(bpw + 1024);
    int kb = (w * 32 + kg * 8) * 2;
    int sw = (e16 & 7) << 4;
#pragma unroll
    for (int g = 0; g < 4; ++g) {
      bf8 bx = *(const bf8*)(xbf + (g * 16 + e16) * 128 + (kb ^ sw));
      macc[g][0] = __builtin_amdgcn_mfma_f32_16x16x32_bf16(Bb0, bx, macc[g][0], 0, 0, 0);
      macc[g][1] = __builtin_amdgcn_mfma_f32_16x16x32_bf16(Bb1, bx, macc[g][1], 0, 0, 0);
      macc[g][2] = __builtin_amdgcn_mfma_f32_16x16x32_bf16(Bb2, bx, macc[g][2], 0, 0, 0);
    }
  }

  // ---- cross-wave reduction through LDS (red overlays hls/xbf) ----
  __syncthreads();
  if (w < 2) {
#pragma unroll
    for (int g = 0; g < 4; ++g)
#pragma unroll
      for (int f = 0; f < 3; ++f)
        *(f4*)&red[((size_t)w * 64 + g * 16 + e16) * 52 + f * 16 + kg * 4] = macc[g][f];
  }
  __syncthreads();
  if (w >= 2) {
#pragma unroll
    for (int g = 0; g < 4; ++g)
#pragma unroll
      for (int f = 0; f < 3; ++f) {
        float* rp = &red[((size_t)(w - 2) * 64 + g * 16 + e16) * 52 + f * 16 + kg * 4];
        f4 v = *(f4*)rp;
        v += macc[g][f];
        *(f4*)rp = v;
      }
  }
  __syncthreads();
  {
    int e = tid >> 2, c = tid & 3;
    if (e < ne) {
      float* mrow = msg + (size_t)(et + e) * MS;
#pragma unroll
      for (int u = 0; u < 3; ++u) {
        int o0 = c * 12 + u * 4;
        f4 v0 = *(f4*)&red[(size_t)e * 52 + o0];
        f4 v1 = *(f4*)&red[((size_t)(64 + e)) * 52 + o0];
        f4 s = v0 + v1;
        *(f4*)(mrow + o0) = s;   // cols >= 42 are pad; node kernel ignores
      }
    }
  }
#undef COMPUTE
#undef LOADA
}

// ---------------------------------------------------------------------------
// Node update with fused CSR aggregation:
// aggr = sum over msg rows [rs[n], rs[n+1]); m = relu(aggr + out + conv_bias);
// out_new = concat([m, out]) @ msg_w + msg_b;  last step: d_out = out_new + n_feat
// CSR gather is 4-wide with clamped indices so 4 independent loads are in
// flight per iteration.
// ---------------------------------------------------------------------------
__global__ void k_node_update(const float* __restrict__ msg, const int* __restrict__ rs,
                              const float* __restrict__ outp,
                              const float* __restrict__ cb, const float* __restrict__ mw,
                              const float* __restrict__ mb, float* __restrict__ newout,
                              const float* __restrict__ nf, void* __restrict__ fout,
                              int last, const int* __restrict__ flag) {
  int gid = blockIdx.x * blockDim.x + threadIdx.x;
  int n = gid >> 6, lane = gid & 63;
  if (n >= NN) return;
  float ov = (lane < D) ? outp[(size_t)n * D + lane] : 0.f;
  float av = 0.f;
  int r0 = rs[n], r1 = rs[n + 1];
  if (lane < D && r0 < r1) {
    float a0 = 0.f, a1 = 0.f, a2 = 0.f, a3 = 0.f;
    for (int r = r0; r < r1; r += 4) {
      int i1 = (r + 1 < r1) ? r + 1 : r;
      int i2 = (r + 2 < r1) ? r + 2 : r;
      int i3 = (r + 3 < r1) ? r + 3 : r;
      float v0 = msg[(size_t)r  * MS + lane];
      float v1 = msg[(size_t)i1 * MS + lane];
      float v2 = msg[(size_t)i2 * MS + lane];
      float v3 = msg[(size_t)i3 * MS + lane];
      a0 += v0;
      a1 += (r + 1 < r1) ? v1 : 0.f;
      a2 += (r + 2 < r1) ? v2 : 0.f;
      a3 += (r + 3 < r1) ? v3 : 0.f;
    }
    av = (a0 + a1) + (a2 + a3);
  }
  float mv = 0.f;
  if (lane < D) mv = fmaxf(av + ov + cb[lane], 0.f);
  if (lane < D) {
    float acc = mb[lane];
    for (int i = 0; i < D; ++i)
      acc += __shfl(mv, i, 64) * mw[i * D + lane];
    for (int i = 0; i < D; ++i)
      acc += __shfl(ov, i, 64) * mw[(D + i) * D + lane];
    size_t idx = (size_t)n * D + lane;
    if (last) {
      float res = acc + nf[idx];
      if (flag[0]) ((u16*)fout)[idx] = f2bf(res);
      else         ((float*)fout)[idx] = res;
    } else {
      newout[idx] = acc;
    }
  }
}

// ---------------------------------------------------------------------------
extern "C" void kernel_launch(void* const* d_in, const int* in_sizes, int n_in,
                              void* d_out, int out_size, void* d_ws, size_t ws_size,
                              hipStream_t stream) {
  (void)in_sizes; (void)n_in; (void)out_size; (void)ws_size;
  const void* nf   = d_in[0];
  const void* ef   = d_in[1];
  const int*  srcI = (const int*)d_in[2];
  const int*  dstI = (const int*)d_in[3];
  const void* l0w = d_in[4];  const void* l0b = d_in[5];
  const void* e1w = d_in[6];  const void* e1b = d_in[7];
  const void* e2w = d_in[8];  const void* e2b = d_in[9];
  const void* cbI = d_in[10]; const void* mwI = d_in[11]; const void* mbI = d_in[12];

  char* ws = (char*)d_ws;
  size_t off = 0;
  auto alloc = [&](size_t bytes) -> void* {
    void* p = ws + off;
    off = (off + bytes + 255) & ~(size_t)255;
    return p;
  };

  int*   flag  = (int*)alloc(4);
  float* c_nf  = (float*)alloc((size_t)NN * D * 4);
  float* c_ef  = (float*)alloc((size_t)NE * 10 * 4);
  float* c_l0w = (float*)alloc(D * D * 4);
  float* c_l0b = (float*)alloc(D * 4);
  float* c_e1w = (float*)alloc(10 * EH * 4);
  float* c_e1b = (float*)alloc(EH * 4);
  float* c_e2w = (float*)alloc((size_t)EH * DD * 4);
  float* c_e2b = (float*)alloc(DD * 4);
  float* c_cb  = (float*)alloc(D * 4);
  float* c_mw  = (float*)alloc(2 * D * D * 4);
  float* c_mb  = (float*)alloc(D * 4);
  float* out_a = (float*)alloc((size_t)NN * D * 4);
  float* out_b = (float*)alloc((size_t)NN * D * 4);
  u16*   hbf   = (u16*)alloc((size_t)NE * EH * 2);
  u16*   Ap    = (u16*)alloc((size_t)D * 4 * 3 * 64 * 8 * 2);
  u16*   b2p   = (u16*)alloc((size_t)2 * 3 * 64 * 8 * 2);
  int*   cnt    = (int*)alloc((size_t)NN * 4);
  int*   loc    = (int*)alloc((size_t)NN * 4);
  int*   part   = (int*)alloc((size_t)SCAN_NB * 4);
  int*   rowst  = (int*)alloc((size_t)(NN + 1) * 4);
  int*   cursor = (int*)alloc((size_t)NN * 4);
  int*   rank   = (int*)alloc((size_t)NE * 4);
  int*   srcS   = (int*)alloc((size_t)NE * 4);
  float* msg    = (float*)alloc((size_t)NE * MS * 4);

  // dtype probe + canonicalization to fp32
  k_detect<<<1, 256, 0, stream>>>((const u32*)nf, flag);
  auto cvt = [&](const void* s, float* dPtr, int count) {
    k_cvt<<<(count + 255) / 256, 256, 0, stream>>>(s, dPtr, count, flag);
  };
  cvt(nf,  c_nf,  NN * D);
  cvt(ef,  c_ef,  NE * 10);
  cvt(l0w, c_l0w, D * D);
  cvt(l0b, c_l0b, D);
  cvt(e1w, c_e1w, 10 * EH);
  cvt(e1b, c_e1b, EH);
  cvt(e2w, c_e2w, EH * DD);
  cvt(e2b, c_e2b, DD);
  cvt(cbI, c_cb,  D);
  cvt(mwI, c_mw,  2 * D * D);
  cvt(mbI, c_mb,  D);

  // CSR build (dst constant across steps — once per launch)
  (void)hipMemsetAsync(cnt, 0, (size_t)NN * 4, stream);
  k_hist<<<(NE + 255) / 256, 256, 0, stream>>>(dstI, cnt);
  k_scanA<<<SCAN_NB, 256, 0, stream>>>(cnt, loc, part);
  k_scanB<<<1, 256, 0, stream>>>(part);
  k_scanC<<<SCAN_NB, 256, 0, stream>>>(loc, part, rowst);
  (void)hipMemcpyAsync(cursor, rowst, (size_t)NN * 4, hipMemcpyDeviceToDevice, stream);
  k_rank<<<(NE + 255) / 256, 256, 0, stream>>>(dstI, srcI, cursor, rank, srcS);

  // node init + edge network (dst-sorted) + fragment packing
  k_lin0<<<(NN * 64 + 255) / 256, 256, 0, stream>>>(c_nf, c_l0w, c_l0b, out_a);
  k_en1<<<(NE * 128 + 255) / 256, 256, 0, stream>>>(c_ef, c_e1w, c_e1b, rank, hbf);
  k_packA<<<(D * 4 * 3 * 64 * 8 + 255) / 256, 256, 0, stream>>>(c_e2w, Ap);
  k_packB2<<<(2 * 3 * 64 * 8 + 255) / 256, 256, 0, stream>>>(c_e2b, b2p);

  int nblk = (NE + 63) / 64;
  float* cur = out_a;
  float* nxt = out_b;
  for (int s = 0; s < STEPS; ++s) {
    k_edge_mfma<<<nblk, 256, 0, stream>>>(cur, hbf, Ap, b2p, srcS, msg);
    int last = (s == STEPS - 1) ? 1 : 0;
    k_node_update<<<(NN * 64 + 255) / 256, 256, 0, stream>>>(
        msg, rowst, cur, c_cb, c_mw, c_mb, nxt, c_nf, d_out, last, flag);
    float* t = cur; cur = nxt; nxt = t;
  }
}

// Round 7
// 945.233 us; speedup vs baseline: 1.0614x; 1.0052x over previous
//
#include <hip/hip_runtime.h>

typedef unsigned short u16;
typedef unsigned int u32;

#define NN 50000
#define NE 150000
#define D 42
#define EH 128
#define DD 1764   // D*D
#define STEPS 6
#define MS 48     // msg row stride (floats), 192 B = 16B-aligned
#define SCAN_NB 196  // (NN + 255) / 256

typedef __attribute__((ext_vector_type(8))) short bf8;
typedef __attribute__((ext_vector_type(4))) float f4;

static __device__ __forceinline__ float bf2f(u16 v) {
  return __uint_as_float(((u32)v) << 16);
}
static __device__ __forceinline__ u16 f2bf(float f) {
  u32 x = __float_as_uint(f);
  return (u16)((x + 0x7fffu + ((x >> 16) & 1u)) >> 16);  // RNE
}

// ---------------------------------------------------------------------------
// Dtype probe (bf16 vs fp32 inputs).
// ---------------------------------------------------------------------------
__global__ void k_detect(const u32* __restrict__ words, int* __restrict__ flag) {
  __shared__ int cnt;
  if (threadIdx.x == 0) cnt = 0;
  __syncthreads();
  int bad = 0;
  for (int i = threadIdx.x; i < 4096; i += 256) {
    u32 w = words[i];
    float v = __uint_as_float((w & 0xffffu) << 16);
    float a = fabsf(v);
    if (!(a < 16.0f)) bad++;
  }
  if (bad) atomicAdd(&cnt, bad);
  __syncthreads();
  if (threadIdx.x == 0) flag[0] = (cnt < 100) ? 1 : 0;
}

__global__ void k_cvt(const void* __restrict__ src, float* __restrict__ dst,
                      int count, const int* __restrict__ flag) {
  int i = blockIdx.x * blockDim.x + threadIdx.x;
  if (i >= count) return;
  if (flag[0]) dst[i] = bf2f(((const u16*)src)[i]);
  else         dst[i] = ((const float*)src)[i];
}

// ---------------------------------------------------------------------------
// CSR build: histogram of dst, hierarchical scan to row starts, rank assign.
// dst is constant across the 6 steps so this is once per launch.
// ---------------------------------------------------------------------------
__global__ void k_hist(const int* __restrict__ dstI, int* __restrict__ cnt) {
  int e = blockIdx.x * blockDim.x + threadIdx.x;
  if (e < NE) atomicAdd(&cnt[dstI[e]], 1);
}

// Phase A: per-block (256-wide) inclusive scan; block sums -> part[].
__global__ void k_scanA(const int* __restrict__ cnt, int* __restrict__ loc,
                        int* __restrict__ part) {
  __shared__ int wsum[4];
  int tid = threadIdx.x, wid = tid >> 6, lane = tid & 63;
  int i = blockIdx.x * 256 + tid;
  int v = (i < NN) ? cnt[i] : 0;
#pragma unroll
  for (int d = 1; d < 64; d <<= 1) {
    int t = __shfl_up(v, d, 64);
    if (lane >= d) v += t;
  }
  if (lane == 63) wsum[wid] = v;
  __syncthreads();
  if (tid == 0) {
    int s = 0;
#pragma unroll
    for (int w2 = 0; w2 < 4; ++w2) { int t = wsum[w2]; wsum[w2] = s; s += t; }
    part[blockIdx.x] = s;
  }
  __syncthreads();
  v += wsum[wid];
  if (i < NN) loc[i] = v;
}

// Phase B: single-block exclusive scan of part[SCAN_NB] in place.
__global__ void k_scanB(int* __restrict__ part) {
  __shared__ int wsum[4];
  int tid = threadIdx.x, wid = tid >> 6, lane = tid & 63;
  int v = (tid < SCAN_NB) ? part[tid] : 0;
  int orig = v;
#pragma unroll
  for (int d = 1; d < 64; d <<= 1) {
    int t = __shfl_up(v, d, 64);
    if (lane >= d) v += t;
  }
  if (lane == 63) wsum[wid] = v;
  __syncthreads();
  if (tid == 0) {
    int s = 0;
#pragma unroll
    for (int w2 = 0; w2 < 4; ++w2) { int t = wsum[w2]; wsum[w2] = s; s += t; }
  }
  __syncthreads();
  v += wsum[wid];
  if (tid < SCAN_NB) part[tid] = v - orig;  // exclusive
}

// Phase C: rs[0] = 0; rs[i+1] = loc[i] + part[i>>8].
__global__ void k_scanC(const int* __restrict__ loc, const int* __restrict__ part,
                        int* __restrict__ rs) {
  int i = blockIdx.x * 256 + threadIdx.x;
  if (i == 0) rs[0] = 0;
  if (i < NN) rs[i + 1] = loc[i] + part[blockIdx.x];
}

// rank[e] = sorted position of edge e; srcS[rank[e]] = src[e].
__global__ void k_rank(const int* __restrict__ dstI, const int* __restrict__ srcI,
                       int* __restrict__ cursor, int* __restrict__ rank,
                       int* __restrict__ srcS) {
  int e = blockIdx.x * blockDim.x + threadIdx.x;
  if (e >= NE) return;
  int p = atomicAdd(&cursor[dstI[e]], 1);
  rank[e] = p;
  srcS[p] = srcI[e];
}

// ---------------------------------------------------------------------------
// out0 = relu(n_feat @ lin0_w + lin0_b).  One wave per node, lane = out col.
// ---------------------------------------------------------------------------
__global__ void k_lin0(const float* __restrict__ nf, const float* __restrict__ w,
                       const float* __restrict__ b, float* __restrict__ outp) {
  int gid = blockIdx.x * blockDim.x + threadIdx.x;
  int n = gid >> 6, lane = gid & 63;
  if (n >= NN) return;
  float xv = (lane < D) ? nf[(size_t)n * D + lane] : 0.f;
  if (lane < D) {
    float acc = b[lane];
    for (int i = 0; i < D; ++i)
      acc += __shfl(xv, i, 64) * w[i * D + lane];
    outp[(size_t)n * D + lane] = fmaxf(acc, 0.f);
  }
}

// ---------------------------------------------------------------------------
// h_e = relu(e_feat @ en1_w + en1_b) -> bf16 [E][128], written in dst-sorted
// order (row rank[e]).
// ---------------------------------------------------------------------------
__global__ void k_en1(const float* __restrict__ ef, const float* __restrict__ w,
                      const float* __restrict__ b, const int* __restrict__ rank,
                      u16* __restrict__ h) {
  int gid = blockIdx.x * blockDim.x + threadIdx.x;
  int e = gid >> 7, k = gid & 127;
  if (e >= NE) return;
  float acc = b[k];
#pragma unroll
  for (int i = 0; i < 10; ++i)
    acc += ef[(size_t)e * 10 + i] * w[i * EH + k];
  h[(size_t)rank[e] * EH + k] = f2bf(fmaxf(acc, 0.f));
}

// ---------------------------------------------------------------------------
// Pack w2 into MFMA A-fragment order (bf16).
// A-frag for i-slice, kstep s, o-frag f: lane l holds 8 elems:
//   row o = f*16 + (l&15), k = s*32 + (l>>4)*8 + j,  value = w2[k, i, o]
// Element offset = (((i*4 + s)*3 + f)*64 + l)*8 + j.
// ---------------------------------------------------------------------------
__global__ void k_packA(const float* __restrict__ w2, u16* __restrict__ Ap) {
  int idx = blockIdx.x * 256 + threadIdx.x;
  if (idx >= D * 4 * 3 * 64 * 8) return;
  int j = idx & 7;
  int t = idx >> 3;
  int l = t & 63; t >>= 6;
  int f = t % 3;  t /= 3;
  int s = t & 3;
  int i = t >> 2;
  int k = s * 32 + ((l >> 4) << 3) + j;
  int o = f * 16 + (l & 15);
  float v = (o < D) ? w2[(size_t)k * DD + i * D + o] : 0.f;
  Ap[idx] = f2bf(v);
}

// b2 (en2_b reshaped [42][42]) packed as A-frags: row o, k = i-index.
__global__ void k_packB2(const float* __restrict__ e2b, u16* __restrict__ b2p) {
  int idx = blockIdx.x * 256 + threadIdx.x;
  if (idx >= 2 * 3 * 64 * 8) return;
  int j = idx & 7;
  int t = idx >> 3;
  int l = t & 63; t >>= 6;
  int f = t % 3;
  int s = t / 3;
  int k = s * 32 + ((l >> 4) << 3) + j;
  int o = f * 16 + (l & 15);
  float v = (k < D && o < D) ? e2b[k * D + o] : 0.f;
  b2p[idx] = f2bf(v);
}

// ---------------------------------------------------------------------------
// Fused NNConv message kernel, MFMA path. Edges are dst-sorted; messages are
// written LINEARLY to msg[E][MS] (no atomics).
//
// Round-3 decomposition (proven): wave = kstep (4-way K-split), 4 edge-groups
// per wave, LDS 2-stage reduction. A-frags prefetch depth 2 (4 buffers).
// R6's v_pk_fma_f32 inline-asm accumulate produced NaN -> reverted to the
// proven scalar-fmac COMPUTE (this kernel is byte-identical to R5's).
// WRITE_SIZE == 28125 KB is the no-spill sentinel.
// __launch_bounds__(256,3): (256,4) caps VGPR at 64 -> spills (proven R1).
// ---------------------------------------------------------------------------
__launch_bounds__(256, 3)
__global__ void k_edge_mfma(const float* __restrict__ outp, const u16* __restrict__ hbf,
                            const u16* __restrict__ Ap, const u16* __restrict__ b2p,
                            const int* __restrict__ srcS, float* __restrict__ msg) {
  // LDS: xT [42][64] f32 (10752 B) | region2: {hls 16KB + xbf 8KB} later {red [2][64][52] f32 = 26624 B}
  __shared__ __align__(16) char smem[10752 + 26624];
  float* xT = (float*)smem;
  char*  hls = smem + 10752;
  char*  xbf = smem + 10752 + 16384;
  float* red = (float*)(smem + 10752);

  int tid = threadIdx.x;
  long et = (long)blockIdx.x * 64;
  int ne = (int)(NE - et); if (ne > 64) ne = 64;

  // ---- stage h tile [64][128] bf16, XOR-swizzled rows ----
  for (int c = tid; c < 1024; c += 256) {
    int row = c >> 4;
    int off = (c & 15) << 4;  // byte offset within 256B row
    uint4 v = {0, 0, 0, 0};
    if (row < ne) v = *(const uint4*)(hbf + (et + row) * EH + (off >> 1));
    *(uint4*)(hls + row * 256 + (off ^ ((row & 7) << 4))) = v;
  }
  // ---- stage x = out[srcS[p]]: xT transposed f32 + xbf row-major bf16 (swizzled) ----
  {
    int r = tid >> 2, j = tid & 3;
    const float* xr = (r < ne) ? (outp + (size_t)srcS[et + r] * D) : nullptr;
    for (int i = j; i < D; i += 4) {
      float v = xr ? xr[i] : 0.f;
      xT[i * 64 + r] = v;
      int bo = (r * 128 + i * 2) ^ ((r & 7) << 4);
      *(u16*)(xbf + bo) = f2bf(v);
    }
    for (int i = D + j; i < 64; i += 4) {
      int bo = (r * 128 + i * 2) ^ ((r & 7) << 4);
      *(u16*)(xbf + bo) = 0;
    }
  }
  __syncthreads();

  int w = tid >> 6;   // wave id = k-step
  int l = tid & 63;
  int e16 = l & 15;
  int kg = l >> 4;

  // ---- hoist h B-frags (one k-step, 4 edge-groups) into registers ----
  bf8 hf[4];
  {
    int kb = (w * 32 + kg * 8) * 2;
    int sw = (e16 & 7) << 4;
#pragma unroll
    for (int g = 0; g < 4; ++g)
      hf[g] = *(const bf8*)(hls + (g * 16 + e16) * 256 + (kb ^ sw));
  }

  f4 macc[4][3];
#pragma unroll
  for (int g = 0; g < 4; ++g)
#pragma unroll
    for (int f = 0; f < 3; ++f)
      macc[g][f] = (f4){0.f, 0.f, 0.f, 0.f};

  const u16* apw = Ap + (size_t)w * 1536 + (size_t)l * 8;

#define LOADA(dst, ii)                                                          \
  {                                                                             \
    const u16* p_ = apw + (size_t)(ii) * 6144;                                  \
    dst[0] = *(const bf8*)(p_);                                                 \
    dst[1] = *(const bf8*)(p_ + 512);                                           \
    dst[2] = *(const bf8*)(p_ + 1024);                                          \
  }

#define COMPUTE(ii, AA)                                                         \
  {                                                                             \
    _Pragma("unroll")                                                           \
    for (int g = 0; g < 4; ++g) {                                               \
      float xs = xT[(ii) * 64 + g * 16 + e16];                                  \
      f4 zz = {0.f, 0.f, 0.f, 0.f};                                             \
      f4 q0 = __builtin_amdgcn_mfma_f32_16x16x32_bf16(AA[0], hf[g], zz, 0, 0, 0); \
      f4 q1 = __builtin_amdgcn_mfma_f32_16x16x32_bf16(AA[1], hf[g], zz, 0, 0, 0); \
      f4 q2 = __builtin_amdgcn_mfma_f32_16x16x32_bf16(AA[2], hf[g], zz, 0, 0, 0); \
      macc[g][0] += xs * q0;                                                    \
      macc[g][1] += xs * q1;                                                    \
      macc[g][2] += xs * q2;                                                    \
    }                                                                           \
  }

  // ---- main loop over 42 i-slices, 4-buffer rotation, prefetch depth 2 ----
  bf8 B0[3], B1[3], B2[3], B3[3];
  LOADA(B0, 0); LOADA(B1, 1); LOADA(B2, 2); LOADA(B3, 3);
#pragma unroll 1
  for (int i = 0; i < 40; i += 4) {
    COMPUTE(i, B0);     { int n0 = i + 4; if (n0 >= D) n0 = 0; LOADA(B0, n0); }
    COMPUTE(i + 1, B1); { int n1 = i + 5; if (n1 >= D) n1 = 0; LOADA(B1, n1); }
    COMPUTE(i + 2, B2); { int n2 = i + 6; if (n2 >= D) n2 = 0; LOADA(B2, n2); }
    COMPUTE(i + 3, B3); { int n3 = i + 7; if (n3 >= D) n3 = 0; LOADA(B3, n3); }
  }
  COMPUTE(40, B0);
  COMPUTE(41, B1);

  // ---- b2 epilogue: waves 0,1 add (x @ b2)^T via 2 k-steps over i ----
  if (w < 2) {
    const u16* bpw = b2p + (size_t)w * 1536 + (size_t)l * 8;
    bf8 Bb0 = *(const bf8*)(bpw);
    bf8 Bb1 = *(const bf8*)(bpw + 512);
    bf8 Bb2 = *(const bf8*)(bpw + 1024);
    int kb = (w * 32 + kg * 8) * 2;
    int sw = (e16 & 7) << 4;
#pragma unroll
    for (int g = 0; g < 4; ++g) {
      bf8 bx = *(const bf8*)(xbf + (g * 16 + e16) * 128 + (kb ^ sw));
      macc[g][0] = __builtin_amdgcn_mfma_f32_16x16x32_bf16(Bb0, bx, macc[g][0], 0, 0, 0);
      macc[g][1] = __builtin_amdgcn_mfma_f32_16x16x32_bf16(Bb1, bx, macc[g][1], 0, 0, 0);
      macc[g][2] = __builtin_amdgcn_mfma_f32_16x16x32_bf16(Bb2, bx, macc[g][2], 0, 0, 0);
    }
  }

  // ---- cross-wave reduction through LDS (red overlays hls/xbf) ----
  __syncthreads();
  if (w < 2) {
#pragma unroll
    for (int g = 0; g < 4; ++g)
#pragma unroll
      for (int f = 0; f < 3; ++f)
        *(f4*)&red[((size_t)w * 64 + g * 16 + e16) * 52 + f * 16 + kg * 4] = macc[g][f];
  }
  __syncthreads();
  if (w >= 2) {
#pragma unroll
    for (int g = 0; g < 4; ++g)
#pragma unroll
      for (int f = 0; f < 3; ++f) {
        float* rp = &red[((size_t)(w - 2) * 64 + g * 16 + e16) * 52 + f * 16 + kg * 4];
        f4 v = *(f4*)rp;
        v += macc[g][f];
        *(f4*)rp = v;
      }
  }
  __syncthreads();
  {
    int e = tid >> 2, c = tid & 3;
    if (e < ne) {
      float* mrow = msg + (size_t)(et + e) * MS;
#pragma unroll
      for (int u = 0; u < 3; ++u) {
        int o0 = c * 12 + u * 4;
        f4 v0 = *(f4*)&red[(size_t)e * 52 + o0];
        f4 v1 = *(f4*)&red[((size_t)(64 + e)) * 52 + o0];
        f4 s = v0 + v1;
        *(f4*)(mrow + o0) = s;   // cols >= 42 are pad; node kernel ignores
      }
    }
  }
#undef COMPUTE
#undef LOADA
}

// ---------------------------------------------------------------------------
// Node update with fused CSR aggregation:
// aggr = sum over msg rows [rs[n], rs[n+1]); m = relu(aggr + out + conv_bias);
// out_new = concat([m, out]) @ msg_w + msg_b;  last step: d_out = out_new + n_feat
// CSR gather is 4-wide with clamped indices (4 loads in flight).
// Matmul fully unrolled with 4 independent accumulators: old version compiled
// to VGPR=16 — one load + serial fmac chain at a time, latency-exposed.
// ---------------------------------------------------------------------------
__global__ void k_node_update(const float* __restrict__ msg, const int* __restrict__ rs,
                              const float* __restrict__ outp,
                              const float* __restrict__ cb, const float* __restrict__ mw,
                              const float* __restrict__ mb, float* __restrict__ newout,
                              const float* __restrict__ nf, void* __restrict__ fout,
                              int last, const int* __restrict__ flag) {
  int gid = blockIdx.x * blockDim.x + threadIdx.x;
  int n = gid >> 6, lane = gid & 63;
  if (n >= NN) return;
  float ov = (lane < D) ? outp[(size_t)n * D + lane] : 0.f;
  float av = 0.f;
  int r0 = rs[n], r1 = rs[n + 1];
  if (lane < D && r0 < r1) {
    float a0 = 0.f, a1 = 0.f, a2 = 0.f, a3 = 0.f;
    for (int r = r0; r < r1; r += 4) {
      int i1 = (r + 1 < r1) ? r + 1 : r;
      int i2 = (r + 2 < r1) ? r + 2 : r;
      int i3 = (r + 3 < r1) ? r + 3 : r;
      float v0 = msg[(size_t)r  * MS + lane];
      float v1 = msg[(size_t)i1 * MS + lane];
      float v2 = msg[(size_t)i2 * MS + lane];
      float v3 = msg[(size_t)i3 * MS + lane];
      a0 += v0;
      a1 += (r + 1 < r1) ? v1 : 0.f;
      a2 += (r + 2 < r1) ? v2 : 0.f;
      a3 += (r + 3 < r1) ? v3 : 0.f;
    }
    av = (a0 + a1) + (a2 + a3);
  }
  float mv = 0.f;
  if (lane < D) mv = fmaxf(av + ov + cb[lane], 0.f);
  if (lane < D) {
    float ac0 = mb[lane], ac1 = 0.f, ac2 = 0.f, ac3 = 0.f;
#pragma unroll
    for (int i = 0; i < 40; i += 4) {
      ac0 += __shfl(mv, i,     64) * mw[i * D + lane];
      ac1 += __shfl(mv, i + 1, 64) * mw[(i + 1) * D + lane];
      ac2 += __shfl(mv, i + 2, 64) * mw[(i + 2) * D + lane];
      ac3 += __shfl(mv, i + 3, 64) * mw[(i + 3) * D + lane];
    }
    ac0 += __shfl(mv, 40, 64) * mw[40 * D + lane];
    ac1 += __shfl(mv, 41, 64) * mw[41 * D + lane];
#pragma unroll
    for (int i = 0; i < 40; i += 4) {
      ac0 += __shfl(ov, i,     64) * mw[(D + i) * D + lane];
      ac1 += __shfl(ov, i + 1, 64) * mw[(D + i + 1) * D + lane];
      ac2 += __shfl(ov, i + 2, 64) * mw[(D + i + 2) * D + lane];
      ac3 += __shfl(ov, i + 3, 64) * mw[(D + i + 3) * D + lane];
    }
    ac0 += __shfl(ov, 40, 64) * mw[(D + 40) * D + lane];
    ac1 += __shfl(ov, 41, 64) * mw[(D + 41) * D + lane];
    float acc = (ac0 + ac1) + (ac2 + ac3);
    size_t idx = (size_t)n * D + lane;
    if (last) {
      float res = acc + nf[idx];
      if (flag[0]) ((u16*)fout)[idx] = f2bf(res);
      else         ((float*)fout)[idx] = res;
    } else {
      newout[idx] = acc;
    }
  }
}

// ---------------------------------------------------------------------------
extern "C" void kernel_launch(void* const* d_in, const int* in_sizes, int n_in,
                              void* d_out, int out_size, void* d_ws, size_t ws_size,
                              hipStream_t stream) {
  (void)in_sizes; (void)n_in; (void)out_size; (void)ws_size;
  const void* nf   = d_in[0];
  const void* ef   = d_in[1];
  const int*  srcI = (const int*)d_in[2];
  const int*  dstI = (const int*)d_in[3];
  const void* l0w = d_in[4];  const void* l0b = d_in[5];
  const void* e1w = d_in[6];  const void* e1b = d_in[7];
  const void* e2w = d_in[8];  const void* e2b = d_in[9];
  const void* cbI = d_in[10]; const void* mwI = d_in[11]; const void* mbI = d_in[12];

  char* ws = (char*)d_ws;
  size_t off = 0;
  auto alloc = [&](size_t bytes) -> void* {
    void* p = ws + off;
    off = (off + bytes + 255) & ~(size_t)255;
    return p;
  };

  int*   flag  = (int*)alloc(4);
  float* c_nf  = (float*)alloc((size_t)NN * D * 4);
  float* c_ef  = (float*)alloc((size_t)NE * 10 * 4);
  float* c_l0w = (float*)alloc(D * D * 4);
  float* c_l0b = (float*)alloc(D * 4);
  float* c_e1w = (float*)alloc(10 * EH * 4);
  float* c_e1b = (float*)alloc(EH * 4);
  float* c_e2w = (float*)alloc((size_t)EH * DD * 4);
  float* c_e2b = (float*)alloc(DD * 4);
  float* c_cb  = (float*)alloc(D * 4);
  float* c_mw  = (float*)alloc(2 * D * D * 4);
  float* c_mb  = (float*)alloc(D * 4);
  float* out_a = (float*)alloc((size_t)NN * D * 4);
  float* out_b = (float*)alloc((size_t)NN * D * 4);
  u16*   hbf   = (u16*)alloc((size_t)NE * EH * 2);
  u16*   Ap    = (u16*)alloc((size_t)D * 4 * 3 * 64 * 8 * 2);
  u16*   b2p   = (u16*)alloc((size_t)2 * 3 * 64 * 8 * 2);
  int*   cnt    = (int*)alloc((size_t)NN * 4);
  int*   loc    = (int*)alloc((size_t)NN * 4);
  int*   part   = (int*)alloc((size_t)SCAN_NB * 4);
  int*   rowst  = (int*)alloc((size_t)(NN + 1) * 4);
  int*   cursor = (int*)alloc((size_t)NN * 4);
  int*   rank   = (int*)alloc((size_t)NE * 4);
  int*   srcS   = (int*)alloc((size_t)NE * 4);
  float* msg    = (float*)alloc((size_t)NE * MS * 4);

  // dtype probe + canonicalization to fp32
  k_detect<<<1, 256, 0, stream>>>((const u32*)nf, flag);
  auto cvt = [&](const void* s, float* dPtr, int count) {
    k_cvt<<<(count + 255) / 256, 256, 0, stream>>>(s, dPtr, count, flag);
  };
  cvt(nf,  c_nf,  NN * D);
  cvt(ef,  c_ef,  NE * 10);
  cvt(l0w, c_l0w, D * D);
  cvt(l0b, c_l0b, D);
  cvt(e1w, c_e1w, 10 * EH);
  cvt(e1b, c_e1b, EH);
  cvt(e2w, c_e2w, EH * DD);
  cvt(e2b, c_e2b, DD);
  cvt(cbI, c_cb,  D);
  cvt(mwI, c_mw,  2 * D * D);
  cvt(mbI, c_mb,  D);

  // CSR build (dst constant across steps — once per launch)
  (void)hipMemsetAsync(cnt, 0, (size_t)NN * 4, stream);
  k_hist<<<(NE + 255) / 256, 256, 0, stream>>>(dstI, cnt);
  k_scanA<<<SCAN_NB, 256, 0, stream>>>(cnt, loc, part);
  k_scanB<<<1, 256, 0, stream>>>(part);
  k_scanC<<<SCAN_NB, 256, 0, stream>>>(loc, part, rowst);
  (void)hipMemcpyAsync(cursor, rowst, (size_t)NN * 4, hipMemcpyDeviceToDevice, stream);
  k_rank<<<(NE + 255) / 256, 256, 0, stream>>>(dstI, srcI, cursor, rank, srcS);

  // node init + edge network (dst-sorted) + fragment packing
  k_lin0<<<(NN * 64 + 255) / 256, 256, 0, stream>>>(c_nf, c_l0w, c_l0b, out_a);
  k_en1<<<(NE * 128 + 255) / 256, 256, 0, stream>>>(c_ef, c_e1w, c_e1b, rank, hbf);
  k_packA<<<(D * 4 * 3 * 64 * 8 + 255) / 256, 256, 0, stream>>>(c_e2w, Ap);
  k_packB2<<<(2 * 3 * 64 * 8 + 255) / 256, 256, 0, stream>>>(c_e2b, b2p);

  int nblk = (NE + 63) / 64;
  float* cur = out_a;
  float* nxt = out_b;
  for (int s = 0; s < STEPS; ++s) {
    k_edge_mfma<<<nblk, 256, 0, stream>>>(cur, hbf, Ap, b2p, srcS, msg);
    int last = (s == STEPS - 1) ? 1 : 0;
    k_node_update<<<(NN * 64 + 255) / 256, 256, 0, stream>>>(
        msg, rowst, cur, c_cb, c_mw, c_mb, nxt, c_nf, d_out, last, flag);
    float* t = cur; cur = nxt; nxt = t;
  }
}

// Round 8
// 768.369 us; speedup vs baseline: 1.3057x; 1.2302x over previous
//
#include <hip/hip_runtime.h>

typedef unsigned short u16;
typedef unsigned int u32;

#define NN 50000
#define NE 150000
#define D 42
#define EH 128
#define DD 1764   // D*D
#define STEPS 6
#define MS 48     // msg row stride (floats), 192 B = 16B-aligned
#define OS 48     // out-state row stride (floats) so rows are 16B-aligned
#define SCAN_NB 196  // (NN + 255) / 256

typedef __attribute__((ext_vector_type(8))) short bf8;
typedef __attribute__((ext_vector_type(4))) float f4;

static __device__ __forceinline__ float bf2f(u16 v) {
  return __uint_as_float(((u32)v) << 16);
}
static __device__ __forceinline__ u16 f2bf(float f) {
  u32 x = __float_as_uint(f);
  return (u16)((x + 0x7fffu + ((x >> 16) & 1u)) >> 16);  // RNE
}
static __device__ __forceinline__ u32 bfpair(float a, float b) {
  return (u32)f2bf(a) | ((u32)f2bf(b) << 16);
}

// ---------------------------------------------------------------------------
// Dtype probe (bf16 vs fp32 inputs).
// ---------------------------------------------------------------------------
__global__ void k_detect(const u32* __restrict__ words, int* __restrict__ flag) {
  __shared__ int cnt;
  if (threadIdx.x == 0) cnt = 0;
  __syncthreads();
  int bad = 0;
  for (int i = threadIdx.x; i < 4096; i += 256) {
    u32 w = words[i];
    float v = __uint_as_float((w & 0xffffu) << 16);
    float a = fabsf(v);
    if (!(a < 16.0f)) bad++;
  }
  if (bad) atomicAdd(&cnt, bad);
  __syncthreads();
  if (threadIdx.x == 0) flag[0] = (cnt < 100) ? 1 : 0;
}

__global__ void k_cvt(const void* __restrict__ src, float* __restrict__ dst,
                      int count, const int* __restrict__ flag) {
  int i = blockIdx.x * blockDim.x + threadIdx.x;
  if (i >= count) return;
  if (flag[0]) dst[i] = bf2f(((const u16*)src)[i]);
  else         dst[i] = ((const float*)src)[i];
}

// ---------------------------------------------------------------------------
// CSR build: histogram of dst, hierarchical scan to row starts, rank assign.
// dst is constant across the 6 steps so this is once per launch.
// ---------------------------------------------------------------------------
__global__ void k_hist(const int* __restrict__ dstI, int* __restrict__ cnt) {
  int e = blockIdx.x * blockDim.x + threadIdx.x;
  if (e < NE) atomicAdd(&cnt[dstI[e]], 1);
}

// Phase A: per-block (256-wide) inclusive scan; block sums -> part[].
__global__ void k_scanA(const int* __restrict__ cnt, int* __restrict__ loc,
                        int* __restrict__ part) {
  __shared__ int wsum[4];
  int tid = threadIdx.x, wid = tid >> 6, lane = tid & 63;
  int i = blockIdx.x * 256 + tid;
  int v = (i < NN) ? cnt[i] : 0;
#pragma unroll
  for (int d = 1; d < 64; d <<= 1) {
    int t = __shfl_up(v, d, 64);
    if (lane >= d) v += t;
  }
  if (lane == 63) wsum[wid] = v;
  __syncthreads();
  if (tid == 0) {
    int s = 0;
#pragma unroll
    for (int w2 = 0; w2 < 4; ++w2) { int t = wsum[w2]; wsum[w2] = s; s += t; }
    part[blockIdx.x] = s;
  }
  __syncthreads();
  v += wsum[wid];
  if (i < NN) loc[i] = v;
}

// Phase B: single-block exclusive scan of part[SCAN_NB] in place.
__global__ void k_scanB(int* __restrict__ part) {
  __shared__ int wsum[4];
  int tid = threadIdx.x, wid = tid >> 6, lane = tid & 63;
  int v = (tid < SCAN_NB) ? part[tid] : 0;
  int orig = v;
#pragma unroll
  for (int d = 1; d < 64; d <<= 1) {
    int t = __shfl_up(v, d, 64);
    if (lane >= d) v += t;
  }
  if (lane == 63) wsum[wid] = v;
  __syncthreads();
  if (tid == 0) {
    int s = 0;
#pragma unroll
    for (int w2 = 0; w2 < 4; ++w2) { int t = wsum[w2]; wsum[w2] = s; s += t; }
  }
  __syncthreads();
  v += wsum[wid];
  if (tid < SCAN_NB) part[tid] = v - orig;  // exclusive
}

// Phase C: rs[0] = 0; rs[i+1] = loc[i] + part[i>>8].
__global__ void k_scanC(const int* __restrict__ loc, const int* __restrict__ part,
                        int* __restrict__ rs) {
  int i = blockIdx.x * 256 + threadIdx.x;
  if (i == 0) rs[0] = 0;
  if (i < NN) rs[i + 1] = loc[i] + part[blockIdx.x];
}

// rank[e] = sorted position of edge e; srcS[rank[e]] = src[e].
__global__ void k_rank(const int* __restrict__ dstI, const int* __restrict__ srcI,
                       int* __restrict__ cursor, int* __restrict__ rank,
                       int* __restrict__ srcS) {
  int e = blockIdx.x * blockDim.x + threadIdx.x;
  if (e >= NE) return;
  int p = atomicAdd(&cursor[dstI[e]], 1);
  rank[e] = p;
  srcS[p] = srcI[e];
}

// ---------------------------------------------------------------------------
// out0 = relu(n_feat @ lin0_w + lin0_b).  One wave per node, lane = out col.
// Writes stride OS (=48) so node rows are f4-aligned.
// ---------------------------------------------------------------------------
__global__ void k_lin0(const float* __restrict__ nf, const float* __restrict__ w,
                       const float* __restrict__ b, float* __restrict__ outp) {
  int gid = blockIdx.x * blockDim.x + threadIdx.x;
  int n = gid >> 6, lane = gid & 63;
  if (n >= NN) return;
  float xv = (lane < D) ? nf[(size_t)n * D + lane] : 0.f;
  if (lane < D) {
    float acc = b[lane];
    for (int i = 0; i < D; ++i)
      acc += __shfl(xv, i, 64) * w[i * D + lane];
    outp[(size_t)n * OS + lane] = fmaxf(acc, 0.f);
  }
}

// ---------------------------------------------------------------------------
// h_e = relu(e_feat @ en1_w + en1_b) -> bf16 [E][128], written in dst-sorted
// order (row rank[e]).
// ---------------------------------------------------------------------------
__global__ void k_en1(const float* __restrict__ ef, const float* __restrict__ w,
                      const float* __restrict__ b, const int* __restrict__ rank,
                      u16* __restrict__ h) {
  int gid = blockIdx.x * blockDim.x + threadIdx.x;
  int e = gid >> 7, k = gid & 127;
  if (e >= NE) return;
  float acc = b[k];
#pragma unroll
  for (int i = 0; i < 10; ++i)
    acc += ef[(size_t)e * 10 + i] * w[i * EH + k];
  h[(size_t)rank[e] * EH + k] = f2bf(fmaxf(acc, 0.f));
}

// ---------------------------------------------------------------------------
// Pack w2 into MFMA A-fragment order (bf16).
// A-frag for i-slice, kstep s, o-frag f: lane l holds 8 elems:
//   row o = f*16 + (l&15), k = s*32 + (l>>4)*8 + j,  value = w2[k, i, o]
// Element offset = (((i*4 + s)*3 + f)*64 + l)*8 + j.
// ---------------------------------------------------------------------------
__global__ void k_packA(const float* __restrict__ w2, u16* __restrict__ Ap) {
  int idx = blockIdx.x * 256 + threadIdx.x;
  if (idx >= D * 4 * 3 * 64 * 8) return;
  int j = idx & 7;
  int t = idx >> 3;
  int l = t & 63; t >>= 6;
  int f = t % 3;  t /= 3;
  int s = t & 3;
  int i = t >> 2;
  int k = s * 32 + ((l >> 4) << 3) + j;
  int o = f * 16 + (l & 15);
  float v = (o < D) ? w2[(size_t)k * DD + i * D + o] : 0.f;
  Ap[idx] = f2bf(v);
}

// b2 (en2_b reshaped [42][42]) packed as A-frags: row o, k = i-index.
__global__ void k_packB2(const float* __restrict__ e2b, u16* __restrict__ b2p) {
  int idx = blockIdx.x * 256 + threadIdx.x;
  if (idx >= 2 * 3 * 64 * 8) return;
  int j = idx & 7;
  int t = idx >> 3;
  int l = t & 63; t >>= 6;
  int f = t % 3;
  int s = t / 3;
  int k = s * 32 + ((l >> 4) << 3) + j;
  int o = f * 16 + (l & 15);
  float v = (k < D && o < D) ? e2b[k * D + o] : 0.f;
  b2p[idx] = f2bf(v);
}

// msg_w [84][42] packed as A-frags: 3 ksteps (K=96 padded), 3 o-frags.
__global__ void k_packMW(const float* __restrict__ mw, u16* __restrict__ mwp) {
  int idx = blockIdx.x * 256 + threadIdx.x;
  if (idx >= 3 * 3 * 64 * 8) return;
  int j = idx & 7;
  int t = idx >> 3;
  int l = t & 63; t >>= 6;
  int f = t % 3;
  int s = t / 3;
  int k = s * 32 + ((l >> 4) << 3) + j;
  int o = f * 16 + (l & 15);
  float v = (k < 2 * D && o < D) ? mw[k * D + o] : 0.f;
  mwp[idx] = f2bf(v);
}

// ---------------------------------------------------------------------------
// Fused NNConv message kernel, MFMA path. Edges are dst-sorted; messages are
// written LINEARLY to msg[E][MS] (no atomics).
//
// Round-3 decomposition (proven): wave = kstep (4-way K-split), 4 edge-groups
// per wave, LDS 2-stage reduction. A-frags prefetch depth 2 (4 buffers).
// WRITE_SIZE == 28125 KB is the no-spill sentinel.
// __launch_bounds__(256,3): (256,4) caps VGPR at 64 -> spills (proven R1).
// ---------------------------------------------------------------------------
__launch_bounds__(256, 3)
__global__ void k_edge_mfma(const float* __restrict__ outp, const u16* __restrict__ hbf,
                            const u16* __restrict__ Ap, const u16* __restrict__ b2p,
                            const int* __restrict__ srcS, float* __restrict__ msg) {
  // LDS: xT [42][64] f32 (10752 B) | region2: {hls 16KB + xbf 8KB} later {red [2][64][52] f32 = 26624 B}
  __shared__ __align__(16) char smem[10752 + 26624];
  float* xT = (float*)smem;
  char*  hls = smem + 10752;
  char*  xbf = smem + 10752 + 16384;
  float* red = (float*)(smem + 10752);

  int tid = threadIdx.x;
  long et = (long)blockIdx.x * 64;
  int ne = (int)(NE - et); if (ne > 64) ne = 64;

  // ---- stage h tile [64][128] bf16, XOR-swizzled rows ----
  for (int c = tid; c < 1024; c += 256) {
    int row = c >> 4;
    int off = (c & 15) << 4;  // byte offset within 256B row
    uint4 v = {0, 0, 0, 0};
    if (row < ne) v = *(const uint4*)(hbf + (et + row) * EH + (off >> 1));
    *(uint4*)(hls + row * 256 + (off ^ ((row & 7) << 4))) = v;
  }
  // ---- stage x = out[srcS[p]]: xT transposed f32 + xbf row-major bf16 (swizzled) ----
  {
    int r = tid >> 2, j = tid & 3;
    const float* xr = (r < ne) ? (outp + (size_t)srcS[et + r] * OS) : nullptr;
    for (int i = j; i < D; i += 4) {
      float v = xr ? xr[i] : 0.f;
      xT[i * 64 + r] = v;
      int bo = (r * 128 + i * 2) ^ ((r & 7) << 4);
      *(u16*)(xbf + bo) = f2bf(v);
    }
    for (int i = D + j; i < 64; i += 4) {
      int bo = (r * 128 + i * 2) ^ ((r & 7) << 4);
      *(u16*)(xbf + bo) = 0;
    }
  }
  __syncthreads();

  int w = tid >> 6;   // wave id = k-step
  int l = tid & 63;
  int e16 = l & 15;
  int kg = l >> 4;

  // ---- hoist h B-frags (one k-step, 4 edge-groups) into registers ----
  bf8 hf[4];
  {
    int kb = (w * 32 + kg * 8) * 2;
    int sw = (e16 & 7) << 4;
#pragma unroll
    for (int g = 0; g < 4; ++g)
      hf[g] = *(const bf8*)(hls + (g * 16 + e16) * 256 + (kb ^ sw));
  }

  f4 macc[4][3];
#pragma unroll
  for (int g = 0; g < 4; ++g)
#pragma unroll
    for (int f = 0; f < 3; ++f)
      macc[g][f] = (f4){0.f, 0.f, 0.f, 0.f};

  const u16* apw = Ap + (size_t)w * 1536 + (size_t)l * 8;

#define LOADA(dst, ii)                                                          \
  {                                                                             \
    const u16* p_ = apw + (size_t)(ii) * 6144;                                  \
    dst[0] = *(const bf8*)(p_);                                                 \
    dst[1] = *(const bf8*)(p_ + 512);                                           \
    dst[2] = *(const bf8*)(p_ + 1024);                                          \
  }

#define COMPUTE(ii, AA)                                                         \
  {                                                                             \
    _Pragma("unroll")                                                           \
    for (int g = 0; g < 4; ++g) {                                               \
      float xs = xT[(ii) * 64 + g * 16 + e16];                                  \
      f4 zz = {0.f, 0.f, 0.f, 0.f};                                             \
      f4 q0 = __builtin_amdgcn_mfma_f32_16x16x32_bf16(AA[0], hf[g], zz, 0, 0, 0); \
      f4 q1 = __builtin_amdgcn_mfma_f32_16x16x32_bf16(AA[1], hf[g], zz, 0, 0, 0); \
      f4 q2 = __builtin_amdgcn_mfma_f32_16x16x32_bf16(AA[2], hf[g], zz, 0, 0, 0); \
      macc[g][0] += xs * q0;                                                    \
      macc[g][1] += xs * q1;                                                    \
      macc[g][2] += xs * q2;                                                    \
    }                                                                           \
  }

  // ---- main loop over 42 i-slices, 4-buffer rotation, prefetch depth 2 ----
  bf8 B0[3], B1[3], B2[3], B3[3];
  LOADA(B0, 0); LOADA(B1, 1); LOADA(B2, 2); LOADA(B3, 3);
#pragma unroll 1
  for (int i = 0; i < 40; i += 4) {
    COMPUTE(i, B0);     { int n0 = i + 4; if (n0 >= D) n0 = 0; LOADA(B0, n0); }
    COMPUTE(i + 1, B1); { int n1 = i + 5; if (n1 >= D) n1 = 0; LOADA(B1, n1); }
    COMPUTE(i + 2, B2); { int n2 = i + 6; if (n2 >= D) n2 = 0; LOADA(B2, n2); }
    COMPUTE(i + 3, B3); { int n3 = i + 7; if (n3 >= D) n3 = 0; LOADA(B3, n3); }
  }
  COMPUTE(40, B0);
  COMPUTE(41, B1);

  // ---- b2 epilogue: waves 0,1 add (x @ b2)^T via 2 k-steps over i ----
  if (w < 2) {
    const u16* bpw = b2p + (size_t)w * 1536 + (size_t)l * 8;
    bf8 Bb0 = *(const bf8*)(bpw);
    bf8 Bb1 = *(const bf8*)(bpw + 512);
    bf8 Bb2 = *(const bf8*)(bpw + 1024);
    int kb = (w * 32 + kg * 8) * 2;
    int sw = (e16 & 7) << 4;
#pragma unroll
    for (int g = 0; g < 4; ++g) {
      bf8 bx = *(const bf8*)(xbf + (g * 16 + e16) * 128 + (kb ^ sw));
      macc[g][0] = __builtin_amdgcn_mfma_f32_16x16x32_bf16(Bb0, bx, macc[g][0], 0, 0, 0);
      macc[g][1] = __builtin_amdgcn_mfma_f32_16x16x32_bf16(Bb1, bx, macc[g][1], 0, 0, 0);
      macc[g][2] = __builtin_amdgcn_mfma_f32_16x16x32_bf16(Bb2, bx, macc[g][2], 0, 0, 0);
    }
  }

  // ---- cross-wave reduction through LDS (red overlays hls/xbf) ----
  __syncthreads();
  if (w < 2) {
#pragma unroll
    for (int g = 0; g < 4; ++g)
#pragma unroll
      for (int f = 0; f < 3; ++f)
        *(f4*)&red[((size_t)w * 64 + g * 16 + e16) * 52 + f * 16 + kg * 4] = macc[g][f];
  }
  __syncthreads();
  if (w >= 2) {
#pragma unroll
    for (int g = 0; g < 4; ++g)
#pragma unroll
      for (int f = 0; f < 3; ++f) {
        float* rp = &red[((size_t)(w - 2) * 64 + g * 16 + e16) * 52 + f * 16 + kg * 4];
        f4 v = *(f4*)rp;
        v += macc[g][f];
        *(f4*)rp = v;
      }
  }
  __syncthreads();
  {
    int e = tid >> 2, c = tid & 3;
    if (e < ne) {
      float* mrow = msg + (size_t)(et + e) * MS;
#pragma unroll
      for (int u = 0; u < 3; ++u) {
        int o0 = c * 12 + u * 4;
        f4 v0 = *(f4*)&red[(size_t)e * 52 + o0];
        f4 v1 = *(f4*)&red[((size_t)(64 + e)) * 52 + o0];
        f4 s = v0 + v1;
        *(f4*)(mrow + o0) = s;   // cols >= 42 are pad (exactly 0); node kernel relies on that
      }
    }
  }
#undef COMPUTE
#undef LOADA
}

// ---------------------------------------------------------------------------
// MFMA node update (replaces the shfl-matmul k_node_update, which was
// DS-pipe-bound: 84 ds_bpermute per node-wave ~= 40 us/step).
// Per 64-node block:
//   phase 1: 4 threads/node gather CSR msg rows (f4), m = relu(aggr+out+cb),
//            pack concat([m, out]) as bf16 into cmat[64][96] (row 192 B).
//   phase 2: waves 0..2 each do kstep s=w of K=96: 12 MFMAs vs msg_w A-frags.
//   phase 3: sum the 3 partials from LDS, + msg_b; write newout (stride OS)
//            or, on the last step, d_out dense (+ n_feat residual).
// ---------------------------------------------------------------------------
__launch_bounds__(256, 3)
__global__ void k_node_mfma(const float* __restrict__ msg, const int* __restrict__ rs,
                            const float* __restrict__ outp,
                            const float* __restrict__ cb, const u16* __restrict__ mwp,
                            const float* __restrict__ mb, float* __restrict__ newout,
                            const float* __restrict__ nf, void* __restrict__ fout,
                            int last, const int* __restrict__ flag) {
  __shared__ __align__(16) char smem[12288 + 39936];
  char*  cmat = smem;                    // [64][96] bf16, 192 B rows, no swizzle
  float* red  = (float*)(smem + 12288);  // [3][64][52] f32

  int tid = threadIdx.x;
  int nt = blockIdx.x * 64;
  int nn = NN - nt; if (nn > 64) nn = 64;

  // ---- phase 1: gather + m + bf16 concat pack ----
  {
    int r = tid >> 2, c = tid & 3;   // node-local row, col-quarter (12 cols)
    char* base = cmat + r * 192;
    u32* wm = (u32*)(base + c * 24);        // m pairs: concat cols c*12..
    u32* wo = (u32*)(base + 84 + c * 24);   // out pairs: concat cols 42+c*12..
    if (r < nn) {
      int n = nt + r;
      int r0 = rs[n], r1 = rs[n + 1];
      f4 a0 = {0,0,0,0}, a1 = {0,0,0,0}, a2 = {0,0,0,0};
      for (int row = r0; row < r1; ++row) {
        const float* mr = msg + (size_t)row * MS + c * 12;
        a0 += *(const f4*)(mr);
        a1 += *(const f4*)(mr + 4);
        a2 += *(const f4*)(mr + 8);
      }
      const float* orow = outp + (size_t)n * OS + c * 12;
      f4 o0 = *(const f4*)(orow);
      f4 o1 = *(const f4*)(orow + 4);
      f4 o2 = *(const f4*)(orow + 8);
      const float* cbp = cb + c * 12;   // alloc is 256B-padded; cols>=42 discarded
      f4 m0 = a0 + o0 + *(const f4*)(cbp);
      f4 m1 = a1 + o1 + *(const f4*)(cbp + 4);
      f4 m2 = a2 + o2 + *(const f4*)(cbp + 8);
#pragma unroll
      for (int q = 0; q < 4; ++q) {
        m0[q] = fmaxf(m0[q], 0.f);
        m1[q] = fmaxf(m1[q], 0.f);
        m2[q] = fmaxf(m2[q], 0.f);
      }
      wm[0] = bfpair(m0[0], m0[1]);
      wm[1] = bfpair(m0[2], m0[3]);
      wm[2] = bfpair(m1[0], m1[1]);
      wo[0] = bfpair(o0[0], o0[1]);
      wo[1] = bfpair(o0[2], o0[3]);
      wo[2] = bfpair(o1[0], o1[1]);
      if (c < 3) {   // cols 36..47 only exist up to 41: c==3 packs 6 values
        wm[3] = bfpair(m1[2], m1[3]);
        wm[4] = bfpair(m2[0], m2[1]);
        wm[5] = bfpair(m2[2], m2[3]);
        wo[3] = bfpair(o1[2], o1[3]);
        wo[4] = bfpair(o2[0], o2[1]);
        wo[5] = bfpair(o2[2], o2[3]);
      }
    } else {
      wm[0] = wm[1] = wm[2] = 0;
      wo[0] = wo[1] = wo[2] = 0;
      if (c < 3) { wm[3] = wm[4] = wm[5] = 0; wo[3] = wo[4] = wo[5] = 0; }
    }
    if (c == 0) {   // zero K-pad (concat cols 84..95)
      u32* wp = (u32*)(base + 168);
#pragma unroll
      for (int t2 = 0; t2 < 6; ++t2) wp[t2] = 0;
    }
  }
  __syncthreads();

  int w = tid >> 6;
  int l = tid & 63;
  int e16 = l & 15;
  int kg = l >> 4;

  // ---- phase 2: waves 0..2 each compute one K-step of concat @ msg_w ----
  if (w < 3) {
    bf8 bfr[4];
#pragma unroll
    for (int g = 0; g < 4; ++g)
      bfr[g] = *(const bf8*)(cmat + (g * 16 + e16) * 192 + w * 64 + kg * 16);
    const u16* ap = mwp + (size_t)(w * 3) * 512 + (size_t)l * 8;
    bf8 A0 = *(const bf8*)(ap);
    bf8 A1 = *(const bf8*)(ap + 512);
    bf8 A2 = *(const bf8*)(ap + 1024);
    f4 zz = {0.f, 0.f, 0.f, 0.f};
    float* rw = red + (size_t)w * 3328;
#pragma unroll
    for (int g = 0; g < 4; ++g) {
      f4 c0 = __builtin_amdgcn_mfma_f32_16x16x32_bf16(A0, bfr[g], zz, 0, 0, 0);
      f4 c1 = __builtin_amdgcn_mfma_f32_16x16x32_bf16(A1, bfr[g], zz, 0, 0, 0);
      f4 c2 = __builtin_amdgcn_mfma_f32_16x16x32_bf16(A2, bfr[g], zz, 0, 0, 0);
      float* rp = rw + (size_t)(g * 16 + e16) * 52 + kg * 4;
      *(f4*)(rp)      = c0;
      *(f4*)(rp + 16) = c1;
      *(f4*)(rp + 32) = c2;
    }
  }
  __syncthreads();

  // ---- phase 3: sum 3 K-step partials, + msg_b, write out ----
  {
    int e = tid >> 2, c = tid & 3;
    if (e < nn) {
      int n = nt + e;
#pragma unroll
      for (int u = 0; u < 3; ++u) {
        int o0 = c * 12 + u * 4;
        f4 s = *(f4*)&red[(size_t)e * 52 + o0];
        s += *(f4*)&red[(size_t)(3328 + e * 52) + o0];
        s += *(f4*)&red[(size_t)(6656 + e * 52) + o0];
        s += *(const f4*)(mb + o0);   // alloc 256B-padded; cols>=42 discarded
        if (last) {
#pragma unroll
          for (int q = 0; q < 4; ++q) {
            int oc = o0 + q;
            if (oc < D) {
              size_t idx = (size_t)n * D + oc;
              float res = s[q] + nf[idx];
              if (flag[0]) ((u16*)fout)[idx] = f2bf(res);
              else         ((float*)fout)[idx] = res;
            }
          }
        } else {
          *(f4*)(newout + (size_t)n * OS + o0) = s;  // cols>=42 pad, never read
        }
      }
    }
  }
}

// ---------------------------------------------------------------------------
extern "C" void kernel_launch(void* const* d_in, const int* in_sizes, int n_in,
                              void* d_out, int out_size, void* d_ws, size_t ws_size,
                              hipStream_t stream) {
  (void)in_sizes; (void)n_in; (void)out_size; (void)ws_size;
  const void* nf   = d_in[0];
  const void* ef   = d_in[1];
  const int*  srcI = (const int*)d_in[2];
  const int*  dstI = (const int*)d_in[3];
  const void* l0w = d_in[4];  const void* l0b = d_in[5];
  const void* e1w = d_in[6];  const void* e1b = d_in[7];
  const void* e2w = d_in[8];  const void* e2b = d_in[9];
  const void* cbI = d_in[10]; const void* mwI = d_in[11]; const void* mbI = d_in[12];

  char* ws = (char*)d_ws;
  size_t off = 0;
  auto alloc = [&](size_t bytes) -> void* {
    void* p = ws + off;
    off = (off + bytes + 255) & ~(size_t)255;
    return p;
  };

  int*   flag  = (int*)alloc(4);
  float* c_nf  = (float*)alloc((size_t)NN * D * 4);
  float* c_ef  = (float*)alloc((size_t)NE * 10 * 4);
  float* c_l0w = (float*)alloc(D * D * 4);
  float* c_l0b = (float*)alloc(D * 4);
  float* c_e1w = (float*)alloc(10 * EH * 4);
  float* c_e1b = (float*)alloc(EH * 4);
  float* c_e2w = (float*)alloc((size_t)EH * DD * 4);
  float* c_e2b = (float*)alloc(DD * 4);
  float* c_cb  = (float*)alloc(D * 4);
  float* c_mw  = (float*)alloc(2 * D * D * 4);
  float* c_mb  = (float*)alloc(D * 4);
  float* out_a = (float*)alloc((size_t)NN * OS * 4);
  float* out_b = (float*)alloc((size_t)NN * OS * 4);
  u16*   hbf   = (u16*)alloc((size_t)NE * EH * 2);
  u16*   Ap    = (u16*)alloc((size_t)D * 4 * 3 * 64 * 8 * 2);
  u16*   b2p   = (u16*)alloc((size_t)2 * 3 * 64 * 8 * 2);
  u16*   mwp   = (u16*)alloc((size_t)3 * 3 * 64 * 8 * 2);
  int*   cnt    = (int*)alloc((size_t)NN * 4);
  int*   loc    = (int*)alloc((size_t)NN * 4);
  int*   part   = (int*)alloc((size_t)SCAN_NB * 4);
  int*   rowst  = (int*)alloc((size_t)(NN + 1) * 4);
  int*   cursor = (int*)alloc((size_t)NN * 4);
  int*   rank   = (int*)alloc((size_t)NE * 4);
  int*   srcS   = (int*)alloc((size_t)NE * 4);
  float* msg    = (float*)alloc((size_t)NE * MS * 4);

  // dtype probe + canonicalization to fp32
  k_detect<<<1, 256, 0, stream>>>((const u32*)nf, flag);
  auto cvt = [&](const void* s, float* dPtr, int count) {
    k_cvt<<<(count + 255) / 256, 256, 0, stream>>>(s, dPtr, count, flag);
  };
  cvt(nf,  c_nf,  NN * D);
  cvt(ef,  c_ef,  NE * 10);
  cvt(l0w, c_l0w, D * D);
  cvt(l0b, c_l0b, D);
  cvt(e1w, c_e1w, 10 * EH);
  cvt(e1b, c_e1b, EH);
  cvt(e2w, c_e2w, EH * DD);
  cvt(e2b, c_e2b, DD);
  cvt(cbI, c_cb,  D);
  cvt(mwI, c_mw,  2 * D * D);
  cvt(mbI, c_mb,  D);

  // CSR build (dst constant across steps — once per launch)
  (void)hipMemsetAsync(cnt, 0, (size_t)NN * 4, stream);
  k_hist<<<(NE + 255) / 256, 256, 0, stream>>>(dstI, cnt);
  k_scanA<<<SCAN_NB, 256, 0, stream>>>(cnt, loc, part);
  k_scanB<<<1, 256, 0, stream>>>(part);
  k_scanC<<<SCAN_NB, 256, 0, stream>>>(loc, part, rowst);
  (void)hipMemcpyAsync(cursor, rowst, (size_t)NN * 4, hipMemcpyDeviceToDevice, stream);
  k_rank<<<(NE + 255) / 256, 256, 0, stream>>>(dstI, srcI, cursor, rank, srcS);

  // node init + edge network (dst-sorted) + fragment packing
  k_lin0<<<(NN * 64 + 255) / 256, 256, 0, stream>>>(c_nf, c_l0w, c_l0b, out_a);
  k_en1<<<(NE * 128 + 255) / 256, 256, 0, stream>>>(c_ef, c_e1w, c_e1b, rank, hbf);
  k_packA<<<(D * 4 * 3 * 64 * 8 + 255) / 256, 256, 0, stream>>>(c_e2w, Ap);
  k_packB2<<<(2 * 3 * 64 * 8 + 255) / 256, 256, 0, stream>>>(c_e2b, b2p);
  k_packMW<<<(3 * 3 * 64 * 8 + 255) / 256, 256, 0, stream>>>(c_mw, mwp);

  int nblk = (NE + 63) / 64;
  int nblkN = (NN + 63) / 64;
  float* cur = out_a;
  float* nxt = out_b;
  for (int s = 0; s < STEPS; ++s) {
    k_edge_mfma<<<nblk, 256, 0, stream>>>(cur, hbf, Ap, b2p, srcS, msg);
    int last = (s == STEPS - 1) ? 1 : 0;
    k_node_mfma<<<nblkN, 256, 0, stream>>>(
        msg, rowst, cur, c_cb, mwp, c_mb, nxt, c_nf, d_out, last, flag);
    float* t = cur; cur = nxt; nxt = t;
  }
}